// Round 1
// baseline (497.095 us; speedup 1.0000x reference)
//
#include <hip/hip_runtime.h>
#include <hip/hip_bf16.h>
#include <math.h>

#define KCOMP 32
#define DDIM  128
#define NPTS  65536
#define GMM_EPS 1e-6f

typedef __attribute__((ext_vector_type(8)))  __bf16 bf16x8;
typedef __attribute__((ext_vector_type(16))) float  f32x16;

__device__ __forceinline__ unsigned short f2bf(float f){
  unsigned u = __builtin_bit_cast(unsigned, f);
  u = (u + 0x7FFFu + ((u >> 16) & 1u)) >> 16;   // RNE
  return (unsigned short)u;
}

// ---------------------------------------------------------------------------
// K1: per-component Cholesky (L in fp32), half-logdet -> const2, zero ws_mp.
// One block per component, 256 threads. A = cov + eps*I, right-looking chol.
// ---------------------------------------------------------------------------
__global__ __launch_bounds__(256) void k_chol(const float* __restrict__ cov,
                                              const float* __restrict__ wts,
                                              float* __restrict__ wsL,
                                              float* __restrict__ ws_mp,
                                              float* __restrict__ ws_c2){
  __shared__ float A[DDIM*129];
  __shared__ float L[DDIM*129];
  __shared__ float sc[2];
  __shared__ float redl[DDIM];
  const int t = threadIdx.x;
  const int k = blockIdx.x;

  const float4* src = (const float4*)(cov + (size_t)k*DDIM*DDIM);
  #pragma unroll
  for(int v=0; v<16; v++){
    int idx4 = t + 256*v;
    float4 f = src[idx4];
    int e = idx4*4; int i = e>>7; int j = e&127;
    float* d = &A[i*129+j];
    d[0]=f.x; d[1]=f.y; d[2]=f.z; d[3]=f.w;
  }
  if(t < DDIM) ws_mp[k*DDIM + t] = 0.f;   // zero accumulator for K2 atomics
  __syncthreads();
  if(t < DDIM) A[t*129+t] += GMM_EPS;
  __syncthreads();

  const int ty = t>>4, tx = t&15;
  for(int j=0;j<DDIM;j++){
    if(t==0){
      float d  = A[j*129+j];
      float sd = sqrtf(d);
      L[j*129+j] = sd;
      sc[0] = 1.f/sd;
      sc[1] = 1.f/d;
    }
    __syncthreads();
    float rstd = sc[0], invd = sc[1];
    // scale column j into L (A keeps unscaled values; updates use invd)
    for(int i=j+1+t; i<DDIM; i+=256) L[i*129+j] = A[i*129+j]*rstd;
    // rank-1 update of trailing lower triangle
    for(int i=j+1+ty; i<DDIM; i+=16){
      float aij = A[i*129+j]*invd;
      for(int p=j+1+tx; p<=i; p+=16) A[i*129+p] -= aij*A[p*129+j];
    }
    __syncthreads();
  }

  if(t < DDIM) redl[t] = logf(L[t*129+t]);
  __syncthreads();
  if(t==0){
    float hld = 0.f;
    for(int i=0;i<DDIM;i++) hld += redl[i];
    // const2 = log w - halflogdet - 0.5*D*log(2*pi)
    ws_c2[k] = logf(wts[k]) - hld - 117.6241322f;
  }
  float4* dst = (float4*)(wsL + (size_t)k*DDIM*DDIM);
  #pragma unroll
  for(int v=0; v<16; v++){
    int idx4 = t + 256*v; int e = idx4*4; int i = e>>7; int j = e&127;
    const float* s = &L[i*129+j];
    float4 f; f.x=s[0]; f.y=s[1]; f.z=s[2]; f.w=s[3];
    dst[idx4] = f;
  }
}

// ---------------------------------------------------------------------------
// K2: triangular inverse U = L^{-1} (forward substitution), 4 blocks per
// component each owning 32 columns (8 threads/column). Packs U into bf16
// MFMA-frag-major layout and accumulates m' = U*mu into ws_mp via atomics.
// ---------------------------------------------------------------------------
__global__ __launch_bounds__(256) void k_winv(const float* __restrict__ wsL,
                                              const float* __restrict__ means,
                                              float* __restrict__ ws_mp,
                                              unsigned short* __restrict__ ufrag){
  __shared__ float L[DDIM*129];
  __shared__ float Wc[DDIM*33];
  __shared__ float invd[DDIM];
  __shared__ float red2[32*8];
  __shared__ float muS[32];
  const int t  = threadIdx.x;
  const int c  = blockIdx.x;   // column block 0..3
  const int k  = blockIdx.y;
  const int j0 = c*32;

  const float4* src = (const float4*)(wsL + (size_t)k*DDIM*DDIM);
  #pragma unroll
  for(int v=0; v<16; v++){
    int idx4 = t + 256*v; float4 f = src[idx4];
    int e = idx4*4; int i = e>>7; int j = e&127;
    float* d = &L[i*129+j]; d[0]=f.x; d[1]=f.y; d[2]=f.z; d[3]=f.w;
  }
  for(int z=t; z<DDIM*33; z+=256) Wc[z] = 0.f;
  if(t < 32) muS[t] = means[k*DDIM + j0 + t];
  __syncthreads();
  if(t < DDIM) invd[t] = 1.f/L[t*129+t];
  __syncthreads();

  const int col = t&31, sub = t>>5;
  for(int i=0;i<DDIM;i++){
    float part = 0.f;
    for(int p=sub; p<i; p+=8) part += L[i*129+p]*Wc[p*33+col];
    red2[col*8+sub] = part;
    __syncthreads();
    if(sub==0){
      float tot = red2[col*8+0]+red2[col*8+1]+red2[col*8+2]+red2[col*8+3]
                + red2[col*8+4]+red2[col*8+5]+red2[col*8+6]+red2[col*8+7];
      int j = j0+col;
      Wc[i*33+col] = (i==j) ? invd[i] : -tot*invd[i];   // 0 for i<j (tot==0)
    }
    __syncthreads();
  }

  // pack this block's 32 columns into frag-major bf16:
  // slot(kc,itile,l): B[k=kc*16+(l>>5)*8+jj][n=itile*32+(l&31)] = U[n][k]
  #pragma unroll
  for(int u=0; u<2; u++){
    int s    = t + 256*u;            // 0..511
    int kc   = 2*c + (s>>8);
    int rem  = s & 255;
    int itile= rem >> 6;
    int l    = rem & 63;
    int i    = itile*32 + (l&31);
    int jl   = (s>>8)*16 + ((l>>5)*8);   // local col in Wc
    unsigned short b[8];
    #pragma unroll
    for(int jj=0;jj<8;jj++) b[jj] = f2bf(Wc[i*33 + jl + jj]);
    uint4 w;
    w.x = (unsigned)b[0] | ((unsigned)b[1]<<16);
    w.y = (unsigned)b[2] | ((unsigned)b[3]<<16);
    w.z = (unsigned)b[4] | ((unsigned)b[5]<<16);
    w.w = (unsigned)b[6] | ((unsigned)b[7]<<16);
    ((uint4*)ufrag)[(size_t)k*2048 + ((kc*4+itile)*64 + l)] = w;
  }
  // partial m' = U[:, j0:j0+32] * mu[j0:j0+32]
  if(t < DDIM){
    float s2 = 0.f;
    #pragma unroll
    for(int jl=0;jl<32;jl++) s2 += Wc[t*33+jl]*muS[jl];
    atomicAdd(&ws_mp[k*DDIM + t], s2);
  }
}

// ---------------------------------------------------------------------------
// Main: per block 128 points. X -> bf16 frag-major LDS once; loop k:
// stage U_k (reg double-buffered), GEMM G = X*U_k^T with 32x32x16 bf16 MFMA,
// epilogue sum_i (G - m')^2 into swizzled LDS partials, 128 lse threads keep
// online logsumexp state.
// ---------------------------------------------------------------------------
__global__ __launch_bounds__(256,2) void k_main(const float* __restrict__ x,
                                                const uint4* __restrict__ uf,
                                                const float* __restrict__ ws_mp,
                                                const float* __restrict__ ws_c2,
                                                float* __restrict__ out){
  __shared__ short Xs[16384];          // 32 KB: X frags
  __shared__ short Us[16384];          // 32 KB: U_k frags
  __shared__ float mahabuf[DDIM*32];   // 16 KB: swizzled row partials
  const int t    = threadIdx.x;
  const int lane = t & 63, wv = t >> 6;
  const size_t n0 = (size_t)blockIdx.x * 128;

  // --- X tile -> bf16 frag-major ---
  const float4* xb = (const float4*)(x + n0*DDIM);
  #pragma unroll
  for(int v=0; v<16; v++){
    int idx4 = t + 256*v;
    float4 f = xb[idx4];
    int e = idx4*4; int p = e>>7; int j = e&127;
    int slot = ((j>>4)*4 + (p>>5))*64 + ((p&31) | (((j>>3)&1)<<5));
    short4 h;
    h.x = (short)f2bf(f.x); h.y = (short)f2bf(f.y);
    h.z = (short)f2bf(f.z); h.w = (short)f2bf(f.w);
    *(short4*)&Xs[slot*8 + (j&7)] = h;
  }
  // prefetch U_0 into registers
  uint4 ur[8];
  #pragma unroll
  for(int v=0; v<8; v++) ur[v] = uf[t + 256*v];

  const int ma = (wv>>1)*2, ia = (wv&1)*2;       // wave's mtile/itile base
  const int cc = lane & 31, q = lane >> 5, half = wv & 1;
  float m_run = -INFINITY, s_run = 0.f;

  for(int k=0;k<KCOMP;k++){
    __syncthreads();  // B1: prev MFMA U-reads + epilogue writes complete
    if(k>0 && t<128){
      float mh = 0.f;
      #pragma unroll
      for(int s=0;s<32;s++) mh += mahabuf[t*32 + ((s+t)&31)];
      float a  = ws_c2[k-1] - 0.5f*mh;
      float nm = fmaxf(m_run, a);
      s_run = s_run*__expf(m_run-nm) + __expf(a-nm);
      m_run = nm;
    }
    // write U_k to LDS from regs, prefetch U_{k+1}
    #pragma unroll
    for(int v=0; v<8; v++) *(uint4*)&Us[(t + 256*v)*8] = ur[v];
    if(k < KCOMP-1){
      #pragma unroll
      for(int v=0; v<8; v++) ur[v] = uf[(size_t)(k+1)*2048 + t + 256*v];
    }
    __syncthreads();  // B2: U_k staged, lse reads done
    float mp0 = ws_mp[k*DDIM + ia*32 + cc];
    float mp1 = ws_mp[k*DDIM + (ia+1)*32 + cc];

    f32x16 acc00 = {}, acc01 = {}, acc10 = {}, acc11 = {};
    #pragma unroll
    for(int kc=0;kc<8;kc++){
      bf16x8 a0 = *(const bf16x8*)&Xs[((kc*4+ma  )*64 + lane)*8];
      bf16x8 a1 = *(const bf16x8*)&Xs[((kc*4+ma+1)*64 + lane)*8];
      bf16x8 b0 = *(const bf16x8*)&Us[((kc*4+ia  )*64 + lane)*8];
      bf16x8 b1 = *(const bf16x8*)&Us[((kc*4+ia+1)*64 + lane)*8];
      acc00 = __builtin_amdgcn_mfma_f32_32x32x16_bf16(a0,b0,acc00,0,0,0);
      acc01 = __builtin_amdgcn_mfma_f32_32x32x16_bf16(a0,b1,acc01,0,0,0);
      acc10 = __builtin_amdgcn_mfma_f32_32x32x16_bf16(a1,b0,acc10,0,0,0);
      acc11 = __builtin_amdgcn_mfma_f32_32x32x16_bf16(a1,b1,acc11,0,0,0);
    }
    // epilogue: v = (g-m')^2 summed over this wave's 64 cols, pair-merged
    #pragma unroll
    for(int r=0;r<16;r++){
      float d00 = acc00[r]-mp0, d01 = acc01[r]-mp1;
      float d10 = acc10[r]-mp0, d11 = acc11[r]-mp1;
      float v0 = d00*d00 + d01*d01;
      float v1 = d10*d10 + d11*d11;
      v0 += __shfl_xor(v0, 1);
      v1 += __shfl_xor(v1, 1);
      if(!(cc&1)){
        int row0 = ma*32 + (r&3) + 8*(r>>2) + 4*q;
        int slot = half*16 + (cc>>1);
        mahabuf[row0*32 + ((slot+row0)&31)] = v0;
        int row1 = row0 + 32;
        mahabuf[row1*32 + ((slot+row1)&31)] = v1;
      }
    }
  }
  __syncthreads();
  if(t<128){
    float mh = 0.f;
    #pragma unroll
    for(int s=0;s<32;s++) mh += mahabuf[t*32 + ((s+t)&31)];
    float a  = ws_c2[KCOMP-1] - 0.5f*mh;
    float nm = fmaxf(m_run, a);
    s_run = s_run*__expf(m_run-nm) + __expf(a-nm);
    m_run = nm;
    out[n0 + t] = m_run + logf(s_run);
  }
}

// ---------------------------------------------------------------------------
extern "C" void kernel_launch(void* const* d_in, const int* in_sizes, int n_in,
                              void* d_out, int out_size, void* d_ws, size_t ws_size,
                              hipStream_t stream){
  const float* x   = (const float*)d_in[0];
  const float* mu  = (const float*)d_in[1];
  const float* cov = (const float*)d_in[2];
  const float* wts = (const float*)d_in[3];
  float* out = (float*)d_out;
  char*  ws  = (char*)d_ws;

  float*          wsL  = (float*)(ws);                          // 2 MB (L fp32)
  float*          wsMP = (float*)(ws + 2097152);                // 16 KB (m')
  float*          wsC2 = (float*)(ws + 2097152 + 16384);        // 128 B (const2)
  unsigned short* wsUF = (unsigned short*)(ws + 2097152 + 16384 + 256); // 1 MB (U bf16 frags)

  k_chol<<<KCOMP, 256, 0, stream>>>(cov, wts, wsL, wsMP, wsC2);
  k_winv<<<dim3(4, KCOMP), 256, 0, stream>>>(wsL, mu, wsMP, wsUF);
  k_main<<<NPTS/128, 256, 0, stream>>>(x, (const uint4*)wsUF, wsMP, wsC2, out);
}

// Round 3
// 423.473 us; speedup vs baseline: 1.1739x; 1.1739x over previous
//
#include <hip/hip_runtime.h>
#include <hip/hip_bf16.h>
#include <math.h>

#define KCOMP 32
#define DDIM  128
#define NPTS  65536
#define GMM_EPS 1e-6f

typedef __attribute__((ext_vector_type(8)))  __bf16 bf16x8;
typedef __attribute__((ext_vector_type(16))) float  f32x16;

__device__ __forceinline__ unsigned short f2bf(float f){
  unsigned u = __builtin_bit_cast(unsigned, f);
  u = (u + 0x7FFFu + ((u >> 16) & 1u)) >> 16;   // RNE
  return (unsigned short)u;
}

// ---------------------------------------------------------------------------
// P1: wave-synchronous left-looking Cholesky. One 64-lane wave per component.
// Lane t owns rows {t, 127-t}. Writes L (row-major) to wsL, const2 to ws_c2.
// ---------------------------------------------------------------------------
__global__ __launch_bounds__(64) void k_chol(const float* __restrict__ cov,
                                             const float* __restrict__ wts,
                                             float* __restrict__ wsL,
                                             float* __restrict__ ws_c2){
  __shared__ float A[DDIM*132];
  __shared__ float bc[1];
  const int t = threadIdx.x;            // 0..63
  const int k = blockIdx.x;

  const float4* src = (const float4*)(cov + (size_t)k*DDIM*DDIM);
  #pragma unroll 4
  for(int v=0; v<64; v++){
    int idx4 = t + 64*v; int e = idx4*4; int i = e>>7; int j = e&127;
    *(float4*)&A[i*132+j] = src[idx4];
  }
  __syncthreads();
  for(int z=t; z<DDIM; z+=64) A[z*132+z] += GMM_EPS;
  __syncthreads();

  const int r0 = t, r1 = 127 - t;
  for(int j=0;j<DDIM;j++){
    float d0 = 0.f, d1 = 0.f;
    const int nch = j>>2;
    if(r0 >= j){
      float4 s={0.f,0.f,0.f,0.f};
      for(int c4=0;c4<nch;c4++){
        float4 lj = *(float4*)&A[j*132+4*c4];
        float4 li = *(float4*)&A[r0*132+4*c4];
        s.x += li.x*lj.x; s.y += li.y*lj.y; s.z += li.z*lj.z; s.w += li.w*lj.w;
      }
      d0 = s.x+s.y+s.z+s.w;
      for(int p=nch*4;p<j;p++) d0 += A[r0*132+p]*A[j*132+p];
      d0 = A[r0*132+j] - d0;
    }
    {
      float4 s={0.f,0.f,0.f,0.f};
      if(r1 >= j){
        for(int c4=0;c4<nch;c4++){
          float4 lj = *(float4*)&A[j*132+4*c4];
          float4 li = *(float4*)&A[r1*132+4*c4];
          s.x += li.x*lj.x; s.y += li.y*lj.y; s.z += li.z*lj.z; s.w += li.w*lj.w;
        }
        d1 = s.x+s.y+s.z+s.w;
        for(int p=nch*4;p<j;p++) d1 += A[r1*132+p]*A[j*132+p];
        d1 = A[r1*132+j] - d1;
      }
    }
    if(r0==j){ float sd = sqrtf(d0); A[j*132+j] = sd; bc[0] = 1.f/sd; }
    if(r1==j){ float sd = sqrtf(d1); A[j*132+j] = sd; bc[0] = 1.f/sd; }
    __syncthreads();
    float rstd = bc[0];
    if(r0 > j) A[r0*132+j] = d0*rstd;
    if(r1 > j) A[r1*132+j] = d1*rstd;
    __syncthreads();
  }

  float lacc = logf(A[r0*132+r0]) + logf(A[r1*132+r1]);
  #pragma unroll
  for(int m=1;m<64;m<<=1) lacc += __shfl_xor(lacc, m);
  if(t==0) ws_c2[k] = logf(wts[k]) - lacc - 117.6241322f;

  float4* dst = (float4*)(wsL + (size_t)k*DDIM*DDIM);
  #pragma unroll 4
  for(int v=0; v<64; v++){
    int idx4 = t + 64*v; int e = idx4*4; int i = e>>7; int j = e&127;
    dst[idx4] = *(float4*)&A[i*132+j];
  }
}

// ---------------------------------------------------------------------------
// P2: U = L^{-1}, one lane per column, barrier-free forward substitution.
// Then m' = U*mu, and pack U into bf16 MFMA A-frag layout.
// ---------------------------------------------------------------------------
__global__ __launch_bounds__(128) void k_winv(const float* __restrict__ wsL,
                                              const float* __restrict__ means,
                                              float* __restrict__ ws_mp,
                                              unsigned short* __restrict__ ufrag){
  __shared__ float Lm[DDIM*132];
  __shared__ float Ut[DDIM*132];
  __shared__ float idiag[DDIM];
  __shared__ float muS[DDIM];
  const int t = threadIdx.x;            // 0..127
  const int k = blockIdx.x;

  const float4* src = (const float4*)(wsL + (size_t)k*DDIM*DDIM);
  #pragma unroll 4
  for(int v=0; v<32; v++){
    int idx4 = t + 128*v; float4 f = src[idx4];
    int e = idx4*4; int i = e>>7; int j = e&127;
    *(float4*)&Lm[i*132+j] = f;
  }
  {
    float4 z = {0.f,0.f,0.f,0.f};
    float4* u4 = (float4*)Ut;
    for(int z4=t; z4<DDIM*132/4; z4+=128) u4[z4] = z;
  }
  muS[t] = means[k*DDIM + t];
  __syncthreads();
  idiag[t] = 1.f/Lm[t*132+t];
  __syncthreads();

  const int c  = ((t&63)<<1) | (t>>6);
  const int a0 = c & ~3;
  for(int i=c;i<DDIM;i++){
    float4 s4 = {0.f,0.f,0.f,0.f};
    int p4 = a0;
    for(; p4+4<=i; p4+=4){
      float4 lv = *(float4*)&Lm[i*132+p4];
      float4 uv = *(float4*)&Ut[c*132+p4];
      s4.x += lv.x*uv.x; s4.y += lv.y*uv.y; s4.z += lv.z*uv.z; s4.w += lv.w*uv.w;
    }
    float s = s4.x+s4.y+s4.z+s4.w;
    for(int p=p4;p<i;p++) s += Lm[i*132+p]*Ut[c*132+p];
    float u = ((i==c)?1.f:0.f) - s;
    Ut[c*132+i] = u * idiag[i];
  }
  __syncthreads();

  {
    float s = 0.f;
    for(int cc=0;cc<DDIM;cc++) s += Ut[cc*132+t]*muS[cc];
    ws_mp[k*DDIM + t] = s;
  }
  // pack frags: slot s=(kc*4+dt)*64+l, elem jj = U[dt*32+(l&31)][kc*16+8*(l>>5)+jj]
  #pragma unroll
  for(int u8=0; u8<16; u8++){
    int s   = t + 128*u8;               // 0..2047
    int l   = s&63, dt2 = (s>>6)&3, kc = s>>8;
    int row = dt2*32 + (l&31);
    int colb= kc*16 + ((l>>5)<<3);
    unsigned short b[8];
    #pragma unroll
    for(int jj=0;jj<8;jj++) b[jj] = f2bf(Ut[(colb+jj)*132 + row]);
    uint4 w;
    w.x = (unsigned)b[0] | ((unsigned)b[1]<<16);
    w.y = (unsigned)b[2] | ((unsigned)b[3]<<16);
    w.z = (unsigned)b[4] | ((unsigned)b[5]<<16);
    w.w = (unsigned)b[6] | ((unsigned)b[7]<<16);
    ((uint4*)ufrag)[(size_t)k*2048 + s] = w;
  }
}

// ---------------------------------------------------------------------------
// Main: 256 threads = 4 waves; wave = d-tile dt (32 d's), FULL K=128
// contraction, all 128 points. X register-resident as B-frags (dup across
// waves); U_k streamed from L2 as A-frags. Epilogue: s = sum_r (g-m')^2,
// shfl_xor(32) to merge q-halves, ds_add_f32 into maha[k][n] (4 dt waves).
// 2 barriers total.
// ---------------------------------------------------------------------------
__global__ __launch_bounds__(256,2) void k_main(const float* __restrict__ x,
                                                const uint4* __restrict__ uf,
                                                const float* __restrict__ ws_mp,
                                                const float* __restrict__ ws_c2,
                                                float* __restrict__ out){
  __shared__ float maha[KCOMP*DDIM];   // 16 KB [k][n]
  __shared__ float mpS[KCOMP*DDIM];    // 16 KB [k][d]
  __shared__ float c2s[KCOMP];
  const int t = threadIdx.x, lane = t&63, dt = t>>6;
  const int q = lane>>5, ln = lane&31;
  const size_t n0 = (size_t)blockIdx.x * 128;

  {
    float4 z = {0.f,0.f,0.f,0.f};
    float4* mz = (float4*)maha;
    mz[t] = z; mz[t+256] = z; mz[t+512] = z; mz[t+768] = z;
    const float4* s4 = (const float4*)ws_mp;
    float4* d4 = (float4*)mpS;
    d4[t] = s4[t]; d4[t+256] = s4[t+256]; d4[t+512] = s4[t+512]; d4[t+768] = s4[t+768];
    if(t < KCOMP) c2s[t] = ws_c2[t];
  }

  // X -> bf16 B-frags in registers: xf[it][c] covers point it*32+ln,
  // dims c*16 + 8q + {0..7}. Identical across the 4 waves.
  bf16x8 xf[4][8];
  {
    const float* xb = x + n0*DDIM + 8*q;
    #pragma unroll
    for(int it=0; it<4; it++){
      const float* rowp = xb + (size_t)(it*32 + ln)*DDIM;
      #pragma unroll
      for(int c=0; c<8; c++){
        float4 f0 = *(const float4*)(rowp + c*16);
        float4 f1 = *(const float4*)(rowp + c*16 + 4);
        union { unsigned short us[8]; bf16x8 v; } cv;
        cv.us[0]=f2bf(f0.x); cv.us[1]=f2bf(f0.y); cv.us[2]=f2bf(f0.z); cv.us[3]=f2bf(f0.w);
        cv.us[4]=f2bf(f1.x); cv.us[5]=f2bf(f1.y); cv.us[6]=f2bf(f1.z); cv.us[7]=f2bf(f1.w);
        xf[it][c] = cv.v;
      }
    }
  }
  __syncthreads();

  for(int k=0;k<KCOMP;k++){
    // U_k A-frags for this wave's d-tile (full K): 8 x uint4 from L2/L1
    uint4 ur[8];
    #pragma unroll
    for(int c=0; c<8; c++)
      ur[c] = uf[(size_t)k*2048 + (c*4 + dt)*64 + lane];

    // m' rows: d = dt*32 + (r&3) + 8*(r>>2) + 4q
    const float* mpk = &mpS[k*DDIM + dt*32 + 4*q];
    float4 m0 = *(const float4*)(mpk);
    float4 m1 = *(const float4*)(mpk + 8);
    float4 m2 = *(const float4*)(mpk + 16);
    float4 m3 = *(const float4*)(mpk + 24);
    float mrow[16] = {m0.x,m0.y,m0.z,m0.w, m1.x,m1.y,m1.z,m1.w,
                      m2.x,m2.y,m2.z,m2.w, m3.x,m3.y,m3.z,m3.w};

    #pragma unroll
    for(int g=0; g<2; g++){
      f32x16 a0 = {}, a1 = {};
      #pragma unroll
      for(int c=0; c<8; c++){
        bf16x8 af = __builtin_bit_cast(bf16x8, ur[c]);
        a0 = __builtin_amdgcn_mfma_f32_32x32x16_bf16(af, xf[2*g  ][c], a0, 0,0,0);
        a1 = __builtin_amdgcn_mfma_f32_32x32x16_bf16(af, xf[2*g+1][c], a1, 0,0,0);
      }
      float s0 = 0.f, s1 = 0.f;
      #pragma unroll
      for(int r=0;r<16;r++){
        float d0 = a0[r]-mrow[r]; s0 += d0*d0;
        float d1 = a1[r]-mrow[r]; s1 += d1*d1;
      }
      s0 += __shfl_xor(s0, 32);
      s1 += __shfl_xor(s1, 32);
      if(lane < 32){
        atomicAdd(&maha[k*DDIM + (2*g  )*32 + ln], s0);
        atomicAdd(&maha[k*DDIM + (2*g+1)*32 + ln], s1);
      }
    }
  }
  __syncthreads();

  if(t < 128){
    float m_run = -INFINITY, s_run = 0.f;
    for(int k=0;k<KCOMP;k++){
      float a  = c2s[k] - 0.5f*maha[k*DDIM + t];
      float nm = fmaxf(m_run, a);
      s_run = s_run*__expf(m_run-nm) + __expf(a-nm);
      m_run = nm;
    }
    out[n0 + t] = m_run + logf(s_run);
  }
}

// ---------------------------------------------------------------------------
extern "C" void kernel_launch(void* const* d_in, const int* in_sizes, int n_in,
                              void* d_out, int out_size, void* d_ws, size_t ws_size,
                              hipStream_t stream){
  const float* x   = (const float*)d_in[0];
  const float* mu  = (const float*)d_in[1];
  const float* cov = (const float*)d_in[2];
  const float* wts = (const float*)d_in[3];
  float* out = (float*)d_out;
  char*  ws  = (char*)d_ws;

  float*          wsL  = (float*)(ws);                          // 2 MB (L fp32)
  float*          wsMP = (float*)(ws + 2097152);                // 16 KB (m')
  float*          wsC2 = (float*)(ws + 2097152 + 16384);        // 128 B (const2)
  unsigned short* wsUF = (unsigned short*)(ws + 2097152 + 16384 + 256); // 1 MB (U bf16 frags)

  k_chol<<<KCOMP,  64, 0, stream>>>(cov, wts, wsL, wsC2);
  k_winv<<<KCOMP, 128, 0, stream>>>(wsL, mu, wsMP, wsUF);
  k_main<<<NPTS/128, 256, 0, stream>>>(x, (const uint4*)wsUF, wsMP, wsC2, out);
}

// Round 4
// 353.645 us; speedup vs baseline: 1.4056x; 1.1975x over previous
//
#include <hip/hip_runtime.h>
#include <hip/hip_bf16.h>
#include <math.h>

#define KCOMP 32
#define DDIM  128
#define NPTS  65536
#define GMM_EPS 1e-6f

typedef __attribute__((ext_vector_type(8)))  __bf16 bf16x8;
typedef __attribute__((ext_vector_type(16))) float  f32x16;

__device__ __forceinline__ unsigned short f2bf(float f){
  unsigned u = __builtin_bit_cast(unsigned, f);
  u = (u + 0x7FFFu + ((u >> 16) & 1u)) >> 16;   // RNE
  return (unsigned short)u;
}
__device__ __forceinline__ float rlane(float v, int lsrc){
  return __builtin_bit_cast(float, __builtin_amdgcn_readlane(__builtin_bit_cast(int, v), lsrc));
}
#define F4(arr, idx) (*(float4*)&(arr)[idx])

// ---------------------------------------------------------------------------
// P1: blocked right-looking Cholesky, one block (256 thr) per component.
// Per 32-panel b: fused chol32+inv on wave 0 (readlane broadcast, register
// chain); panel solve L_ib = A_ib V_b^T and SYRK A_ij -= L_ib L_jb^T as
// 4x4-register-tiled LDS GEMMs (one 32^3 unit per wave).
// ---------------------------------------------------------------------------
__global__ __launch_bounds__(256) void k_chol(const float* __restrict__ cov,
                                              const float* __restrict__ wts,
                                              float* __restrict__ wsL,
                                              float* __restrict__ ws_c2){
  __shared__ float A[DDIM*132];        // 67.6 KB, row-major stride 132
  __shared__ float Vbuf[32*36];        // V^T of current diag block
  const int t = threadIdx.x, w = t>>6, l = t&63;
  const int k = blockIdx.x;
  const int r0 = (l>>3)<<2, c0 = (l&7)<<2;

  // load cov -> A (row-major), add eps to diag
  const float4* src = (const float4*)(cov + (size_t)k*DDIM*DDIM);
  #pragma unroll
  for(int v=0; v<16; v++){
    int idx4 = t + 256*v; int e = idx4*4; int i = e>>7; int j = e&127;
    F4(A, i*132+j) = src[idx4];
  }
  __syncthreads();
  if(t < DDIM) A[t*132+t] += GMM_EPS;

  static const int SYI[10] = {1,2,3,2,3,3, 2,3,3, 3};
  static const int SYJ[10] = {1,1,1,2,2,3, 2,2,3, 3};
  static const int SYO[5]  = {0,6,9,10,10};

  for(int b=0; b<4; b++){
    __syncthreads();
    // ---- chol32 + inverse of A_bb, wave 0 lanes 0..31 ----
    if(w==0 && l<32){
      const int i = l;
      float ar[32], lv[32], vv[32];
      #pragma unroll
      for(int a=0; a<8; a++){
        float4 f = F4(A, (32*b+i)*132 + 32*b + 4*a);
        ar[4*a]=f.x; ar[4*a+1]=f.y; ar[4*a+2]=f.z; ar[4*a+3]=f.w;
      }
      #pragma unroll
      for(int j=0; j<32; j++){
        float sc = 0.f, sv = 0.f;
        #pragma unroll
        for(int p=0; p<j; p++){
          float bjp = rlane(lv[p], j);
          sc += lv[p]*bjp;
          sv += vv[p]*bjp;
        }
        float tt  = ar[j] - sc;
        float d   = rlane(tt, j);
        float sd  = sqrtf(d);
        float rsd = 1.0f/sd;
        lv[j] = (i > j) ? tt*rsd : (i==j ? sd : 0.f);
        vv[j] = ((i==j ? 1.f : 0.f) - sv)*rsd;
      }
      // write L row i back; write V^T row i (Vbuf[i][c] = V[c][i] = lane i's vv[c])
      #pragma unroll
      for(int a=0; a<8; a++){
        float4 f; f.x=lv[4*a]; f.y=lv[4*a+1]; f.z=lv[4*a+2]; f.w=lv[4*a+3];
        F4(A, (32*b+i)*132 + 32*b + 4*a) = f;
        float4 g; g.x=vv[4*a]; g.y=vv[4*a+1]; g.z=vv[4*a+2]; g.w=vv[4*a+3];
        F4(Vbuf, i*36 + 4*a) = g;
      }
    }
    __syncthreads();
    // ---- solve: L_ib = A_ib @ Vbuf  (in-place; per-wave unit) ----
    if(w < 3-b){
      const int i = b+1+w;
      float acc[4][4] = {};
      #pragma unroll
      for(int kc=0; kc<8; kc++){
        float a_[4][4], b_[4][4];
        #pragma unroll
        for(int e=0; e<4; e++){
          float4 f = F4(A, (32*i + r0+e)*132 + 32*b + 4*kc);
          a_[e][0]=f.x; a_[e][1]=f.y; a_[e][2]=f.z; a_[e][3]=f.w;
        }
        #pragma unroll
        for(int kk=0; kk<4; kk++){
          float4 f = F4(Vbuf, (4*kc+kk)*36 + c0);
          b_[kk][0]=f.x; b_[kk][1]=f.y; b_[kk][2]=f.z; b_[kk][3]=f.w;
        }
        #pragma unroll
        for(int e=0; e<4; e++)
          #pragma unroll
          for(int f=0; f<4; f++)
            acc[e][f] += a_[e][0]*b_[0][f] + a_[e][1]*b_[1][f]
                       + a_[e][2]*b_[2][f] + a_[e][3]*b_[3][f];
      }
      #pragma unroll
      for(int e=0; e<4; e++){
        float4 o; o.x=acc[e][0]; o.y=acc[e][1]; o.z=acc[e][2]; o.w=acc[e][3];
        F4(A, (32*i + r0+e)*132 + 32*b + c0) = o;
      }
    }
    __syncthreads();
    // ---- SYRK: A_ij -= L_ib @ L_jb^T (dot-form; units round-robin) ----
    for(int u = SYO[b]+w; u < SYO[b+1]; u += 4){
      const int i = SYI[u], j = SYJ[u];
      float acc[4][4] = {};
      #pragma unroll
      for(int kc=0; kc<8; kc++){
        float a_[4][4], b_[4][4];
        #pragma unroll
        for(int e=0; e<4; e++){
          float4 f = F4(A, (32*i + r0+e)*132 + 32*b + 4*kc);
          a_[e][0]=f.x; a_[e][1]=f.y; a_[e][2]=f.z; a_[e][3]=f.w;
        }
        #pragma unroll
        for(int ff=0; ff<4; ff++){
          float4 f = F4(A, (32*j + c0+ff)*132 + 32*b + 4*kc);
          b_[ff][0]=f.x; b_[ff][1]=f.y; b_[ff][2]=f.z; b_[ff][3]=f.w;
        }
        #pragma unroll
        for(int e=0; e<4; e++)
          #pragma unroll
          for(int ff=0; ff<4; ff++)
            acc[e][ff] += a_[e][0]*b_[ff][0] + a_[e][1]*b_[ff][1]
                        + a_[e][2]*b_[ff][2] + a_[e][3]*b_[ff][3];
      }
      #pragma unroll
      for(int e=0; e<4; e++){
        float4 o = F4(A, (32*i + r0+e)*132 + 32*j + c0);
        o.x -= acc[e][0]; o.y -= acc[e][1]; o.z -= acc[e][2]; o.w -= acc[e][3];
        F4(A, (32*i + r0+e)*132 + 32*j + c0) = o;
      }
    }
  }
  __syncthreads();

  // logdet + const2
  float* red = Vbuf;
  if(t < DDIM) red[t] = logf(A[t*132+t]);
  __syncthreads();
  if(t==0){
    float hld = 0.f;
    for(int i=0;i<DDIM;i++) hld += red[i];
    ws_c2[k] = logf(wts[k]) - hld - 117.6241322f;
  }
  // store L
  float4* dst = (float4*)(wsL + (size_t)k*DDIM*DDIM);
  #pragma unroll
  for(int v=0; v<16; v++){
    int idx4 = t + 256*v; int e = idx4*4; int i = e>>7; int j = e&127;
    dst[idx4] = F4(A, i*132+j);
  }
}

// ---------------------------------------------------------------------------
// P2: blocked U = L^{-1}, one block (256 thr) per component, row-major U.
// Base: 4 diag-block inverses via readlane register chains (wave b = block b).
// Levels: U_ij = -V_i (sum_p L_ip U_pj) as per-wave 32^3 GEMM units.
// Then m' = U*mu (float4 row-dot) and bf16 A-frag pack (contiguous rows).
// ---------------------------------------------------------------------------
__global__ __launch_bounds__(256) void k_winv(const float* __restrict__ wsL,
                                              const float* __restrict__ means,
                                              float* __restrict__ ws_mp,
                                              unsigned short* __restrict__ ufrag){
  __shared__ float Lr[DDIM*132];       // 67.6 KB row-major L
  __shared__ float Ur[DDIM*132];       // 67.6 KB row-major U
  __shared__ float Tbuf[3*32*36];      // 13.8 KB
  __shared__ float muS[DDIM];
  const int t = threadIdx.x, w = t>>6, l = t&63;
  const int k = blockIdx.x;
  const int r0 = (l>>3)<<2, c0 = (l&7)<<2;

  const float4* src = (const float4*)(wsL + (size_t)k*DDIM*DDIM);
  #pragma unroll
  for(int v=0; v<16; v++){
    int idx4 = t + 256*v; int e = idx4*4; int i = e>>7; int j = e&127;
    F4(Lr, i*132+j) = src[idx4];
  }
  {
    float4 z = {0.f,0.f,0.f,0.f};
    for(int z4 = t; z4 < DDIM*132/4; z4 += 256) ((float4*)Ur)[z4] = z;
  }
  if(t < DDIM) muS[t] = means[k*DDIM + t];
  __syncthreads();

  // ---- base: invert diag block b on wave b (lanes 0..31) ----
  if(l < 32){
    const int b = w, c = l;
    float ar[32], vv[32];
    #pragma unroll
    for(int a=0; a<8; a++){
      float4 f = F4(Lr, (32*b+l)*132 + 32*b + 4*a);
      ar[4*a]=f.x; ar[4*a+1]=f.y; ar[4*a+2]=f.z; ar[4*a+3]=f.w;
    }
    #pragma unroll
    for(int j=0; j<32; j++){
      float sv = 0.f;
      #pragma unroll
      for(int p=0; p<j; p++) sv += rlane(ar[p], j) * vv[p];
      float d = rlane(ar[j], j);
      vv[j] = ((j==c ? 1.f : 0.f) - sv) / d;
    }
    // write V column c into U diag block (row-major): U[32b+j][32b+c]
    #pragma unroll
    for(int j=0; j<32; j++) Ur[(32*b+j)*132 + 32*b + c] = vv[j];
  }
  __syncthreads();

  // ---- levels ----
  #pragma unroll
  for(int lev=1; lev<=3; lev++){
    const int nu = 4-lev;
    if(w < nu){
      const int j = w, i = w + lev;
      // T = sum_{p=j}^{i-1} L_ip @ U_pj
      float acc[4][4] = {};
      for(int p=j; p<i; p++){
        #pragma unroll
        for(int kc=0; kc<8; kc++){
          float a_[4][4], b_[4][4];
          #pragma unroll
          for(int e=0; e<4; e++){
            float4 f = F4(Lr, (32*i + r0+e)*132 + 32*p + 4*kc);
            a_[e][0]=f.x; a_[e][1]=f.y; a_[e][2]=f.z; a_[e][3]=f.w;
          }
          #pragma unroll
          for(int kk=0; kk<4; kk++){
            float4 f = F4(Ur, (32*p + 4*kc+kk)*132 + 32*j + c0);
            b_[kk][0]=f.x; b_[kk][1]=f.y; b_[kk][2]=f.z; b_[kk][3]=f.w;
          }
          #pragma unroll
          for(int e=0; e<4; e++)
            #pragma unroll
            for(int f=0; f<4; f++)
              acc[e][f] += a_[e][0]*b_[0][f] + a_[e][1]*b_[1][f]
                         + a_[e][2]*b_[2][f] + a_[e][3]*b_[3][f];
        }
      }
      #pragma unroll
      for(int e=0; e<4; e++){
        float4 o; o.x=acc[e][0]; o.y=acc[e][1]; o.z=acc[e][2]; o.w=acc[e][3];
        F4(Tbuf, w*1152 + (r0+e)*36 + c0) = o;
      }
      // U_ij = -V_i @ T   (same wave, own Tbuf region -> no barrier needed)
      float ac2[4][4] = {};
      #pragma unroll
      for(int kc=0; kc<8; kc++){
        float a_[4][4], b_[4][4];
        #pragma unroll
        for(int e=0; e<4; e++){
          float4 f = F4(Ur, (32*i + r0+e)*132 + 32*i + 4*kc);
          a_[e][0]=f.x; a_[e][1]=f.y; a_[e][2]=f.z; a_[e][3]=f.w;
        }
        #pragma unroll
        for(int kk=0; kk<4; kk++){
          float4 f = F4(Tbuf, w*1152 + (4*kc+kk)*36 + c0);
          b_[kk][0]=f.x; b_[kk][1]=f.y; b_[kk][2]=f.z; b_[kk][3]=f.w;
        }
        #pragma unroll
        for(int e=0; e<4; e++)
          #pragma unroll
          for(int f=0; f<4; f++)
            ac2[e][f] += a_[e][0]*b_[0][f] + a_[e][1]*b_[1][f]
                       + a_[e][2]*b_[2][f] + a_[e][3]*b_[3][f];
      }
      #pragma unroll
      for(int e=0; e<4; e++){
        float4 o; o.x=-ac2[e][0]; o.y=-ac2[e][1]; o.z=-ac2[e][2]; o.w=-ac2[e][3];
        F4(Ur, (32*i + r0+e)*132 + 32*j + c0) = o;
      }
    }
    __syncthreads();
  }

  // ---- m' = U*mu (row-major float4 dot) ----
  if(t < DDIM){
    float4 s4 = {0.f,0.f,0.f,0.f};
    #pragma unroll
    for(int a=0; a<32; a++){
      float4 uv = F4(Ur, t*132 + 4*a);
      float4 mv = F4(muS, 4*a);
      s4.x += uv.x*mv.x; s4.y += uv.y*mv.y; s4.z += uv.z*mv.z; s4.w += uv.w*mv.w;
    }
    ws_mp[k*DDIM + t] = (s4.x+s4.y)+(s4.z+s4.w);
  }
  // ---- pack bf16 A-frags: slot s=(kc*4+dt)*64+l2, elem jj = U[dt*32+(l2&31)][kc*16+8*(l2>>5)+jj]
  #pragma unroll
  for(int u8=0; u8<8; u8++){
    int s    = t + 256*u8;              // 0..2047
    int l2   = s&63, dt2 = (s>>6)&3, kc = s>>8;
    int row  = dt2*32 + (l2&31);
    int colb = kc*16 + ((l2>>5)<<3);
    float4 f0 = F4(Ur, row*132 + colb);
    float4 f1 = F4(Ur, row*132 + colb + 4);
    uint4 wv;
    wv.x = (unsigned)f2bf(f0.x) | ((unsigned)f2bf(f0.y)<<16);
    wv.y = (unsigned)f2bf(f0.z) | ((unsigned)f2bf(f0.w)<<16);
    wv.z = (unsigned)f2bf(f1.x) | ((unsigned)f2bf(f1.y)<<16);
    wv.w = (unsigned)f2bf(f1.z) | ((unsigned)f2bf(f1.w)<<16);
    ((uint4*)ufrag)[(size_t)k*2048 + s] = wv;
  }
}

// ---------------------------------------------------------------------------
// Main: unchanged from round 3 (validated). 256 threads = 4 waves = d-tiles,
// full-K contraction per wave, X register-resident, U streamed from L2.
// ---------------------------------------------------------------------------
__global__ __launch_bounds__(256,2) void k_main(const float* __restrict__ x,
                                                const uint4* __restrict__ uf,
                                                const float* __restrict__ ws_mp,
                                                const float* __restrict__ ws_c2,
                                                float* __restrict__ out){
  __shared__ float maha[KCOMP*DDIM];   // 16 KB [k][n]
  __shared__ float mpS[KCOMP*DDIM];    // 16 KB [k][d]
  __shared__ float c2s[KCOMP];
  const int t = threadIdx.x, lane = t&63, dt = t>>6;
  const int q = lane>>5, ln = lane&31;
  const size_t n0 = (size_t)blockIdx.x * 128;

  {
    float4 z = {0.f,0.f,0.f,0.f};
    float4* mz = (float4*)maha;
    mz[t] = z; mz[t+256] = z; mz[t+512] = z; mz[t+768] = z;
    const float4* s4 = (const float4*)ws_mp;
    float4* d4 = (float4*)mpS;
    d4[t] = s4[t]; d4[t+256] = s4[t+256]; d4[t+512] = s4[t+512]; d4[t+768] = s4[t+768];
    if(t < KCOMP) c2s[t] = ws_c2[t];
  }

  bf16x8 xf[4][8];
  {
    const float* xb = x + n0*DDIM + 8*q;
    #pragma unroll
    for(int it=0; it<4; it++){
      const float* rowp = xb + (size_t)(it*32 + ln)*DDIM;
      #pragma unroll
      for(int c=0; c<8; c++){
        float4 f0 = *(const float4*)(rowp + c*16);
        float4 f1 = *(const float4*)(rowp + c*16 + 4);
        union { unsigned short us[8]; bf16x8 v; } cv;
        cv.us[0]=f2bf(f0.x); cv.us[1]=f2bf(f0.y); cv.us[2]=f2bf(f0.z); cv.us[3]=f2bf(f0.w);
        cv.us[4]=f2bf(f1.x); cv.us[5]=f2bf(f1.y); cv.us[6]=f2bf(f1.z); cv.us[7]=f2bf(f1.w);
        xf[it][c] = cv.v;
      }
    }
  }
  __syncthreads();

  for(int k=0;k<KCOMP;k++){
    uint4 ur[8];
    #pragma unroll
    for(int c=0; c<8; c++)
      ur[c] = uf[(size_t)k*2048 + (c*4 + dt)*64 + lane];

    const float* mpk = &mpS[k*DDIM + dt*32 + 4*q];
    float4 m0 = *(const float4*)(mpk);
    float4 m1 = *(const float4*)(mpk + 8);
    float4 m2 = *(const float4*)(mpk + 16);
    float4 m3 = *(const float4*)(mpk + 24);
    float mrow[16] = {m0.x,m0.y,m0.z,m0.w, m1.x,m1.y,m1.z,m1.w,
                      m2.x,m2.y,m2.z,m2.w, m3.x,m3.y,m3.z,m3.w};

    #pragma unroll
    for(int g=0; g<2; g++){
      f32x16 a0 = {}, a1 = {};
      #pragma unroll
      for(int c=0; c<8; c++){
        bf16x8 af = __builtin_bit_cast(bf16x8, ur[c]);
        a0 = __builtin_amdgcn_mfma_f32_32x32x16_bf16(af, xf[2*g  ][c], a0, 0,0,0);
        a1 = __builtin_amdgcn_mfma_f32_32x32x16_bf16(af, xf[2*g+1][c], a1, 0,0,0);
      }
      float s0 = 0.f, s1 = 0.f;
      #pragma unroll
      for(int r=0;r<16;r++){
        float d0 = a0[r]-mrow[r]; s0 += d0*d0;
        float d1 = a1[r]-mrow[r]; s1 += d1*d1;
      }
      s0 += __shfl_xor(s0, 32);
      s1 += __shfl_xor(s1, 32);
      if(lane < 32){
        atomicAdd(&maha[k*DDIM + (2*g  )*32 + ln], s0);
        atomicAdd(&maha[k*DDIM + (2*g+1)*32 + ln], s1);
      }
    }
  }
  __syncthreads();

  if(t < 128){
    float m_run = -INFINITY, s_run = 0.f;
    for(int k=0;k<KCOMP;k++){
      float a  = c2s[k] - 0.5f*maha[k*DDIM + t];
      float nm = fmaxf(m_run, a);
      s_run = s_run*__expf(m_run-nm) + __expf(a-nm);
      m_run = nm;
    }
    out[n0 + t] = m_run + logf(s_run);
  }
}

// ---------------------------------------------------------------------------
extern "C" void kernel_launch(void* const* d_in, const int* in_sizes, int n_in,
                              void* d_out, int out_size, void* d_ws, size_t ws_size,
                              hipStream_t stream){
  const float* x   = (const float*)d_in[0];
  const float* mu  = (const float*)d_in[1];
  const float* cov = (const float*)d_in[2];
  const float* wts = (const float*)d_in[3];
  float* out = (float*)d_out;
  char*  ws  = (char*)d_ws;

  float*          wsL  = (float*)(ws);                          // 2 MB (L fp32)
  float*          wsMP = (float*)(ws + 2097152);                // 16 KB (m')
  float*          wsC2 = (float*)(ws + 2097152 + 16384);        // 128 B (const2)
  unsigned short* wsUF = (unsigned short*)(ws + 2097152 + 16384 + 256); // 1 MB (U bf16 frags)

  k_chol<<<KCOMP, 256, 0, stream>>>(cov, wts, wsL, wsC2);
  k_winv<<<KCOMP, 256, 0, stream>>>(wsL, mu, wsMP, wsUF);
  k_main<<<NPTS/128, 256, 0, stream>>>(x, (const uint4*)wsUF, wsMP, wsC2, out);
}

// Round 5
// 351.709 us; speedup vs baseline: 1.4134x; 1.0055x over previous
//
#include <hip/hip_runtime.h>
#include <hip/hip_bf16.h>
#include <math.h>

#define KCOMP 32
#define DDIM  128
#define NPTS  65536
#define GMM_EPS 1e-6f
#define SA 129   // LDS row stride (odd -> conflict-free column access)

typedef __attribute__((ext_vector_type(8)))  __bf16 bf16x8;
typedef __attribute__((ext_vector_type(16))) float  f32x16;

__device__ __forceinline__ unsigned short f2bf(float f){
  unsigned u = __builtin_bit_cast(unsigned, f);
  u = (u + 0x7FFFu + ((u >> 16) & 1u)) >> 16;   // RNE
  return (unsigned short)u;
}

// ---------------------------------------------------------------------------
// k_prep: one block (256 thr) per component. Blocked Cholesky (32-panels):
// chol32 = left-looking on wave 0, pivot via __shfl, read-only LDS dots;
// panel solve = per-row forward substitution; SYRK = 4x4 reg-tiled read-only
// LDS GEMM. Blocked inverse: per-column diag-inv + level GEMMs. Then m',
// const2, and bf16 MFMA A-frag pack. No per-lane register arrays anywhere.
// ---------------------------------------------------------------------------
__global__ __launch_bounds__(256) void k_prep(const float* __restrict__ cov,
                                              const float* __restrict__ wts,
                                              const float* __restrict__ means,
                                              float* __restrict__ ws_mp,
                                              float* __restrict__ ws_c2,
                                              unsigned short* __restrict__ ufrag){
  __shared__ float A[DDIM*SA];      // 64.5 KB: cov -> L (lower), junk above
  __shared__ float W[DDIM*SA];      // 64.5 KB: U = L^{-1} (lower), 0 above
  __shared__ float Tb[3*32*33];     // 12.4 KB: per-wave level-GEMM scratch
  __shared__ float Drsd[32];        // 1/L[j][j] of current diag block
  __shared__ float sred[DDIM];
  __shared__ float muS[DDIM];
  const int t=threadIdx.x, w=t>>6, l=t&63, k=blockIdx.x;

  const float* cv = cov + (size_t)k*DDIM*DDIM;
  for(int v=t; v<DDIM*DDIM; v+=256) A[(v>>7)*SA+(v&127)] = cv[v];
  for(int v=t; v<DDIM*SA; v+=256) W[v] = 0.f;
  if(t<DDIM) muS[t] = means[k*DDIM+t];
  __syncthreads();
  if(t<DDIM) A[t*SA+t] += GMM_EPS;
  __syncthreads();

  static const int SYI[10]={1,2,2,3,3,3, 2,3,3, 3};
  static const int SYJ[10]={1,1,2,1,2,3, 2,2,3, 3};
  static const int SYO[5] ={0,6,9,10,10};
  const int r0=(l>>3)*4, c0=(l&7)*4;

  #pragma unroll 1
  for(int b=0;b<4;b++){
    const int b32=b*32;
    // ---- chol32 (left-looking), wave 0; lanes 32-63 duplicate harmlessly ----
    if(w==0){
      const int i=l&31;
      #pragma unroll 1
      for(int j=0;j<32;j++){
        float s=0.f;
        for(int p=0;p<j;p++) s += A[(b32+i)*SA+b32+p]*A[(b32+j)*SA+b32+p];
        float c = A[(b32+i)*SA+b32+j] - s;
        float d = __shfl(c, j);
        float rsd = rsqrtf(d);
        float lv = (i==j)? d*rsd : c*rsd;
        if(i>=j) A[(b32+i)*SA+b32+j] = lv;
        if(i==j) Drsd[j] = rsd;
      }
    }
    __syncthreads();
    // ---- panel solve: row r of trailing panel, forward substitution ----
    const int trail = DDIM - 32*(b+1);
    if(t < trail){
      const int i = 32*(b+1)+t;
      #pragma unroll 1
      for(int j=0;j<32;j++){
        float s=0.f;
        for(int p=0;p<j;p++) s += A[i*SA+b32+p]*A[(b32+j)*SA+b32+p];
        A[i*SA+b32+j] = (A[i*SA+b32+j]-s)*Drsd[j];
      }
    }
    __syncthreads();
    // ---- SYRK: A_ij -= L_ib @ L_jb^T (read-only inner loops) ----
    #pragma unroll 1
    for(int u=SYO[b]+w; u<SYO[b+1]; u+=4){
      const int ui=SYI[u], uj=SYJ[u];
      float acc[4][4]={};
      #pragma unroll 1
      for(int kc=0;kc<32;kc+=4){
        float a_[4][4], b_[4][4];
        #pragma unroll
        for(int e=0;e<4;e++){
          #pragma unroll
          for(int g=0;g<4;g++){
            a_[e][g]=A[(32*ui+r0+e)*SA + b32+kc+g];
            b_[e][g]=A[(32*uj+c0+e)*SA + b32+kc+g];
          }
        }
        #pragma unroll
        for(int e=0;e<4;e++)
          #pragma unroll
          for(int f=0;f<4;f++)
            acc[e][f]+=a_[e][0]*b_[f][0]+a_[e][1]*b_[f][1]
                      +a_[e][2]*b_[f][2]+a_[e][3]*b_[f][3];
      }
      #pragma unroll
      for(int e=0;e<4;e++)
        #pragma unroll
        for(int f=0;f<4;f++)
          A[(32*ui+r0+e)*SA+32*uj+c0+f] -= acc[e][f];
    }
    __syncthreads();
  }

  // ---- logdet pieces ----
  if(t<DDIM) sred[t]=logf(A[t*SA+t]);

  // ---- diag-block inverses: thread t -> block t>>5, column t&31 ----
  if(t<DDIM){
    const int d32=(t>>5)*32, c=t&31;
    #pragma unroll 1
    for(int i=c;i<32;i++){
      float s=0.f;
      for(int p=c;p<i;p++) s += A[(d32+i)*SA+d32+p]*W[(d32+p)*SA+d32+c];
      float v=((i==c)?1.f:0.f)-s;
      W[(d32+i)*SA+d32+c]=v/A[(d32+i)*SA+d32+i];
    }
  }
  __syncthreads();

  // ---- levels: U_ij = -V_i (sum_p L_ip U_pj), per-wave 32^3 GEMM units ----
  #pragma unroll 1
  for(int lev=1;lev<=3;lev++){
    if(w<4-lev){
      const int j=w, i=w+lev;
      float* T=&Tb[w*1056];
      float acc[4][4]={};
      #pragma unroll 1
      for(int p=j;p<i;p++){
        #pragma unroll 1
        for(int kc=0;kc<32;kc+=4){
          float a_[4][4], b_[4][4];
          #pragma unroll
          for(int e=0;e<4;e++){
            #pragma unroll
            for(int g=0;g<4;g++){
              a_[e][g]=A[(32*i+r0+e)*SA + 32*p+kc+g];
              b_[e][g]=W[(32*p+kc+e)*SA + 32*j+c0+g];
            }
          }
          #pragma unroll
          for(int e=0;e<4;e++)
            #pragma unroll
            for(int f=0;f<4;f++)
              acc[e][f]+=a_[e][0]*b_[0][f]+a_[e][1]*b_[1][f]
                        +a_[e][2]*b_[2][f]+a_[e][3]*b_[3][f];
        }
      }
      #pragma unroll
      for(int e=0;e<4;e++)
        #pragma unroll
        for(int f=0;f<4;f++)
          T[(r0+e)*33+c0+f]=acc[e][f];
      float ac2[4][4]={};
      #pragma unroll 1
      for(int kc=0;kc<32;kc+=4){
        float a_[4][4], b_[4][4];
        #pragma unroll
        for(int e=0;e<4;e++){
          #pragma unroll
          for(int g=0;g<4;g++){
            a_[e][g]=W[(32*i+r0+e)*SA + 32*i+kc+g];
            b_[e][g]=T[(kc+e)*33 + c0+g];
          }
        }
        #pragma unroll
        for(int e=0;e<4;e++)
          #pragma unroll
          for(int f=0;f<4;f++)
            ac2[e][f]+=a_[e][0]*b_[0][f]+a_[e][1]*b_[1][f]
                      +a_[e][2]*b_[2][f]+a_[e][3]*b_[3][f];
      }
      #pragma unroll
      for(int e=0;e<4;e++)
        #pragma unroll
        for(int f=0;f<4;f++)
          W[(32*i+r0+e)*SA+32*j+c0+f] = -ac2[e][f];
    }
    __syncthreads();
  }

  // ---- m' = U*mu ; const2 ; bf16 A-frag pack ----
  if(t<DDIM){
    float s=0.f;
    for(int c=0;c<DDIM;c++) s+=W[t*SA+c]*muS[c];
    ws_mp[k*DDIM+t]=s;
  }
  if(t==0){
    float h=0.f;
    for(int i=0;i<DDIM;i++) h+=sred[i];
    ws_c2[k]=logf(wts[k])-h-117.6241322f;
  }
  #pragma unroll 1
  for(int s0=t;s0<2048;s0+=256){
    int l2=s0&63, dt2=(s0>>6)&3, kc=s0>>8;
    int row=dt2*32+(l2&31), colb=kc*16+((l2>>5)<<3);
    unsigned uu[4];
    #pragma unroll
    for(int h2=0;h2<4;h2++){
      unsigned lo=f2bf(W[row*SA+colb+2*h2]);
      unsigned hi=f2bf(W[row*SA+colb+2*h2+1]);
      uu[h2]=lo|(hi<<16);
    }
    uint4 wv; wv.x=uu[0]; wv.y=uu[1]; wv.z=uu[2]; wv.w=uu[3];
    ((uint4*)ufrag)[(size_t)k*2048+s0]=wv;
  }
}

// ---------------------------------------------------------------------------
// Main: 256 threads = 4 waves = d-tiles, full-K contraction per wave, X
// register-resident, U streamed from L2 with manual even/odd double buffer.
// ---------------------------------------------------------------------------
#define MAIN_BODY(UR, KK)                                                     \
  {                                                                           \
    const int kidx = (KK);                                                    \
    const float* mpk = &mpS[kidx*DDIM + dt*32 + 4*q];                         \
    float4 m0 = *(const float4*)(mpk);                                        \
    float4 m1 = *(const float4*)(mpk + 8);                                    \
    float4 m2 = *(const float4*)(mpk + 16);                                   \
    float4 m3 = *(const float4*)(mpk + 24);                                   \
    float mrow[16] = {m0.x,m0.y,m0.z,m0.w, m1.x,m1.y,m1.z,m1.w,               \
                      m2.x,m2.y,m2.z,m2.w, m3.x,m3.y,m3.z,m3.w};              \
    _Pragma("unroll")                                                         \
    for(int g=0; g<2; g++){                                                   \
      f32x16 a0 = {}, a1 = {};                                                \
      _Pragma("unroll")                                                       \
      for(int c=0; c<8; c++){                                                 \
        bf16x8 af = __builtin_bit_cast(bf16x8, UR[c]);                        \
        a0 = __builtin_amdgcn_mfma_f32_32x32x16_bf16(af, xf[2*g  ][c], a0, 0,0,0); \
        a1 = __builtin_amdgcn_mfma_f32_32x32x16_bf16(af, xf[2*g+1][c], a1, 0,0,0); \
      }                                                                       \
      float s0 = 0.f, s1 = 0.f;                                               \
      _Pragma("unroll")                                                       \
      for(int r=0;r<16;r++){                                                  \
        float d0 = a0[r]-mrow[r]; s0 += d0*d0;                                \
        float d1 = a1[r]-mrow[r]; s1 += d1*d1;                                \
      }                                                                       \
      s0 += __shfl_xor(s0, 32);                                               \
      s1 += __shfl_xor(s1, 32);                                               \
      if(lane < 32){                                                          \
        atomicAdd(&maha[kidx*DDIM + (2*g  )*32 + ln], s0);                    \
        atomicAdd(&maha[kidx*DDIM + (2*g+1)*32 + ln], s1);                    \
      }                                                                       \
    }                                                                         \
  }

__global__ __launch_bounds__(256,2) void k_main(const float* __restrict__ x,
                                                const uint4* __restrict__ uf,
                                                const float* __restrict__ ws_mp,
                                                const float* __restrict__ ws_c2,
                                                float* __restrict__ out){
  __shared__ float maha[KCOMP*DDIM];   // 16 KB [k][n]
  __shared__ float mpS[KCOMP*DDIM];    // 16 KB [k][d]
  __shared__ float c2s[KCOMP];
  const int t = threadIdx.x, lane = t&63, dt = t>>6;
  const int q = lane>>5, ln = lane&31;
  const size_t n0 = (size_t)blockIdx.x * 128;

  {
    float4 z = {0.f,0.f,0.f,0.f};
    float4* mz = (float4*)maha;
    mz[t] = z; mz[t+256] = z; mz[t+512] = z; mz[t+768] = z;
    const float4* s4 = (const float4*)ws_mp;
    float4* d4 = (float4*)mpS;
    d4[t] = s4[t]; d4[t+256] = s4[t+256]; d4[t+512] = s4[t+512]; d4[t+768] = s4[t+768];
    if(t < KCOMP) c2s[t] = ws_c2[t];
  }

  bf16x8 xf[4][8];
  {
    const float* xb = x + n0*DDIM + 8*q;
    #pragma unroll
    for(int it=0; it<4; it++){
      const float* rowp = xb + (size_t)(it*32 + ln)*DDIM;
      #pragma unroll
      for(int c=0; c<8; c++){
        float4 f0 = *(const float4*)(rowp + c*16);
        float4 f1 = *(const float4*)(rowp + c*16 + 4);
        union { unsigned short us[8]; bf16x8 v; } cvt;
        cvt.us[0]=f2bf(f0.x); cvt.us[1]=f2bf(f0.y); cvt.us[2]=f2bf(f0.z); cvt.us[3]=f2bf(f0.w);
        cvt.us[4]=f2bf(f1.x); cvt.us[5]=f2bf(f1.y); cvt.us[6]=f2bf(f1.z); cvt.us[7]=f2bf(f1.w);
        xf[it][c] = cvt.v;
      }
    }
  }

  uint4 uA[8], uB[8];
  #pragma unroll
  for(int c=0; c<8; c++) uA[c] = uf[(size_t)(c*4 + dt)*64 + lane];
  __syncthreads();

  #pragma unroll 1
  for(int k2=0;k2<KCOMP;k2+=2){
    #pragma unroll
    for(int c=0; c<8; c++)
      uB[c] = uf[(size_t)(k2+1)*2048 + (c*4 + dt)*64 + lane];
    MAIN_BODY(uA, k2)
    {
      const int kn = (k2+2)&(KCOMP-1);   // wraps to 0 on last iter (harmless)
      #pragma unroll
      for(int c=0; c<8; c++)
        uA[c] = uf[(size_t)kn*2048 + (c*4 + dt)*64 + lane];
    }
    MAIN_BODY(uB, k2+1)
  }
  __syncthreads();

  if(t < 128){
    float m_run = -INFINITY, s_run = 0.f;
    #pragma unroll 1
    for(int k=0;k<KCOMP;k++){
      float a  = c2s[k] - 0.5f*maha[k*DDIM + t];
      float nm = fmaxf(m_run, a);
      s_run = s_run*__expf(m_run-nm) + __expf(a-nm);
      m_run = nm;
    }
    out[n0 + t] = m_run + logf(s_run);
  }
}

// ---------------------------------------------------------------------------
extern "C" void kernel_launch(void* const* d_in, const int* in_sizes, int n_in,
                              void* d_out, int out_size, void* d_ws, size_t ws_size,
                              hipStream_t stream){
  const float* x   = (const float*)d_in[0];
  const float* mu  = (const float*)d_in[1];
  const float* cov = (const float*)d_in[2];
  const float* wts = (const float*)d_in[3];
  float* out = (float*)d_out;
  char*  ws  = (char*)d_ws;

  float*          wsMP = (float*)(ws);                 // 16 KB (m')
  float*          wsC2 = (float*)(ws + 16384);         // 128 B (const2)
  unsigned short* wsUF = (unsigned short*)(ws + 16640);// 1 MB (U bf16 frags)

  k_prep<<<KCOMP, 256, 0, stream>>>(cov, wts, mu, wsMP, wsC2, wsUF);
  k_main<<<NPTS/128, 256, 0, stream>>>(x, (const uint4*)wsUF, wsMP, wsC2, out);
}

// Round 6
// 275.080 us; speedup vs baseline: 1.8071x; 1.2786x over previous
//
#include <hip/hip_runtime.h>
#include <hip/hip_bf16.h>
#include <math.h>

#define KCOMP 32
#define DDIM  128
#define NPTS  65536
#define GMM_EPS 1e-6f
#define SA 129   // LDS row stride (odd -> conflict-free for scalar col access)

typedef __attribute__((ext_vector_type(8)))  __bf16 bf16x8;
typedef __attribute__((ext_vector_type(16))) float  f32x16;

__device__ __forceinline__ unsigned short f2bf(float f){
  unsigned u = __builtin_bit_cast(unsigned, f);
  u = (u + 0x7FFFu + ((u >> 16) & 1u)) >> 16;   // RNE
  return (unsigned short)u;
}

// ---------------------------------------------------------------------------
// chol_inv32: register-resident Cholesky + triangular inverse of one 32x32
// SPD block. One wave; lane layout c = lane&31 (column c). ALL array indices
// are compile-time constants -> pure VGPR; cross-lane via __shfl (readlane).
// Writes L rows into Ab (lower, zeros above), V = L^{-1} into Wb (row-major).
// Returns sum_j log L[j][j] (wave-uniform).
// ---------------------------------------------------------------------------
__device__ __noinline__ float chol_inv32(float* __restrict__ Ab,
                                         float* __restrict__ Wb,
                                         const int c){
  float ar[32], lr[32], rd[32], v[32];
  #pragma unroll
  for(int i=0;i<32;i++) ar[i] = Ab[i*SA + c];   // column c (symmetric block)
  float hl = 0.f;
  // right-looking rank-1 Cholesky on the symmetric square: ar[j] (lane c) =
  // A[j][c] = A[c][j]; pivot d = A[j][j] via shfl; no masking needed (stale
  // lanes compute garbage they never use).
  #pragma unroll
  for(int j=0;j<32;j++){
    float d   = __shfl(ar[j], j);       // Schur diag = L[j][j]^2
    float rsd = rsqrtf(d);
    hl += logf(d);
    rd[j] = rsd;                        // 1/L[j][j]
    float Lcj  = ar[j]*rsd;             // L[c][j] (valid for c>=j)
    lr[j] = (c>=j) ? Lcj : 0.f;
    float coef = Lcj*rsd;               // A[c][j]/d
    #pragma unroll
    for(int i=j;i<32;i++){
      float bij = __shfl(ar[i], j);     // A[i][j]
      ar[i] = fmaf(-bij, coef, ar[i]);  // A[i][c] -= L[i][j]*L[c][j]
    }
  }
  #pragma unroll
  for(int j=0;j<32;j++) Ab[c*SA + j] = lr[j];   // row c of L (zeros above diag)
  // forward substitution for V = L^{-1}: v[i] = V[i][c]; v[i]=0 for i<c falls
  // out naturally (s==0). L[i][p] broadcast from lane i's lr[p].
  #pragma unroll
  for(int i=0;i<32;i++){
    float s = (i==c) ? 1.f : 0.f;
    #pragma unroll
    for(int p=0;p<i;p++) s = fmaf(-__shfl(lr[p], i), v[p], s);
    v[i] = s * rd[i];
  }
  #pragma unroll
  for(int i=0;i<32;i++) Wb[i*SA + c] = v[i];
  return 0.5f*hl;
}

// ---------------------------------------------------------------------------
// k_prep: one block (256 thr) per component. Blocked Cholesky+inverse with
// register-resident serial math; panel solve & SYRK & inverse-levels as
// 4x4 reg-tiled LDS GEMMs; then m', const2, bf16 MFMA A-frag pack.
// ---------------------------------------------------------------------------
__global__ __launch_bounds__(256) void k_prep(const float* __restrict__ cov,
                                              const float* __restrict__ wts,
                                              const float* __restrict__ means,
                                              float* __restrict__ ws_mp,
                                              float* __restrict__ ws_c2,
                                              unsigned short* __restrict__ ufrag){
  __shared__ float A[DDIM*SA];      // 64.5 KB: cov -> L (lower)
  __shared__ float W[DDIM*SA];      // 64.5 KB: U = L^{-1} (lower), 0 above
  __shared__ float Tb[3*32*33];     // 12.4 KB: per-wave level-GEMM scratch
  __shared__ float muS[DDIM];
  const int t=threadIdx.x, w=t>>6, l=t&63, k=blockIdx.x;
  const int r0=(l>>3)*4, c0=(l&7)*4;

  // load cov (float4 global) -> A scalar LDS; zero W; stage mu
  const float4* cv4 = (const float4*)(cov + (size_t)k*DDIM*DDIM);
  #pragma unroll
  for(int v=0; v<16; v++){
    int idx4 = t + 256*v; float4 f = cv4[idx4];
    int e = idx4*4; int i = e>>7; int j = e&127;
    float* d = &A[i*SA+j]; d[0]=f.x; d[1]=f.y; d[2]=f.z; d[3]=f.w;
  }
  for(int z=t; z<DDIM*SA; z+=256) W[z] = 0.f;
  if(t<DDIM) muS[t] = means[k*DDIM+t];
  __syncthreads();
  if(t<DDIM) A[t*SA+t] += GMM_EPS;
  __syncthreads();

  static const int SYI[10]={1,2,2,3,3,3, 2,3,3, 3};
  static const int SYJ[10]={1,1,2,1,2,3, 2,2,3, 3};
  static const int SYO[5] ={0,6,9,10,10};

  float hsum = 0.f;
  #pragma unroll 1
  for(int b=0;b<4;b++){
    const int b32=b*32;
    // ---- register chol + inverse of diag block, wave 0 ----
    if(w==0) hsum += chol_inv32(&A[b32*SA+b32], &W[b32*SA+b32], l&31);
    __syncthreads();
    // ---- panel solve: L_ib = A_ib @ V^T  (unit = 32 rows per wave) ----
    if(w < 3-b){
      const int ibl = b+1+w;
      float acc[4][4]={};
      for(int kc=0;kc<32;kc+=4){
        float a_[4][4], b_[4][4];
        #pragma unroll
        for(int e=0;e<4;e++)
          #pragma unroll
          for(int g=0;g<4;g++){
            a_[e][g]=A[(32*ibl+r0+e)*SA + b32+kc+g];
            b_[e][g]=W[(b32+c0+e)*SA   + b32+kc+g];   // V[c0+e][kc+g]
          }
        #pragma unroll
        for(int e=0;e<4;e++)
          #pragma unroll
          for(int f=0;f<4;f++)
            acc[e][f]+=a_[e][0]*b_[f][0]+a_[e][1]*b_[f][1]
                      +a_[e][2]*b_[f][2]+a_[e][3]*b_[f][3];
      }
      // wave-lockstep: all reads above complete before these writes
      #pragma unroll
      for(int e=0;e<4;e++)
        #pragma unroll
        for(int f=0;f<4;f++)
          A[(32*ibl+r0+e)*SA + b32+c0+f] = acc[e][f];
    }
    __syncthreads();
    // ---- SYRK: A_ij -= L_ib @ L_jb^T ----
    #pragma unroll 1
    for(int u=SYO[b]+w; u<SYO[b+1]; u+=4){
      const int ui=SYI[u], uj=SYJ[u];
      float acc[4][4]={};
      for(int kc=0;kc<32;kc+=4){
        float a_[4][4], b_[4][4];
        #pragma unroll
        for(int e=0;e<4;e++)
          #pragma unroll
          for(int g=0;g<4;g++){
            a_[e][g]=A[(32*ui+r0+e)*SA + b32+kc+g];
            b_[e][g]=A[(32*uj+c0+e)*SA + b32+kc+g];
          }
        #pragma unroll
        for(int e=0;e<4;e++)
          #pragma unroll
          for(int f=0;f<4;f++)
            acc[e][f]+=a_[e][0]*b_[f][0]+a_[e][1]*b_[f][1]
                      +a_[e][2]*b_[f][2]+a_[e][3]*b_[f][3];
      }
      #pragma unroll
      for(int e=0;e<4;e++)
        #pragma unroll
        for(int f=0;f<4;f++)
          A[(32*ui+r0+e)*SA+32*uj+c0+f] -= acc[e][f];
    }
    __syncthreads();
  }

  // ---- inverse levels: U_ij = -V_i (sum_p L_ip U_pj) ----
  #pragma unroll 1
  for(int lev=1;lev<=3;lev++){
    if(w<4-lev){
      const int j=w, i=w+lev;
      float* T=&Tb[w*1056];
      float acc[4][4]={};
      #pragma unroll 1
      for(int p=j;p<i;p++){
        for(int kc=0;kc<32;kc+=4){
          float a_[4][4], b_[4][4];
          #pragma unroll
          for(int e=0;e<4;e++)
            #pragma unroll
            for(int g=0;g<4;g++){
              a_[e][g]=A[(32*i+r0+e)*SA + 32*p+kc+g];
              b_[e][g]=W[(32*p+kc+e)*SA + 32*j+c0+g];
            }
          #pragma unroll
          for(int e=0;e<4;e++)
            #pragma unroll
            for(int f=0;f<4;f++)
              acc[e][f]+=a_[e][0]*b_[0][f]+a_[e][1]*b_[1][f]
                        +a_[e][2]*b_[2][f]+a_[e][3]*b_[3][f];
        }
      }
      #pragma unroll
      for(int e=0;e<4;e++)
        #pragma unroll
        for(int f=0;f<4;f++)
          T[(r0+e)*33+c0+f]=acc[e][f];
      float ac2[4][4]={};
      for(int kc=0;kc<32;kc+=4){
        float a_[4][4], b_[4][4];
        #pragma unroll
        for(int e=0;e<4;e++)
          #pragma unroll
          for(int g=0;g<4;g++){
            a_[e][g]=W[(32*i+r0+e)*SA + 32*i+kc+g];
            b_[e][g]=T[(kc+e)*33 + c0+g];
          }
        #pragma unroll
        for(int e=0;e<4;e++)
          #pragma unroll
          for(int f=0;f<4;f++)
            ac2[e][f]+=a_[e][0]*b_[0][f]+a_[e][1]*b_[1][f]
                      +a_[e][2]*b_[2][f]+a_[e][3]*b_[3][f];
      }
      #pragma unroll
      for(int e=0;e<4;e++)
        #pragma unroll
        for(int f=0;f<4;f++)
          W[(32*i+r0+e)*SA+32*j+c0+f] = -ac2[e][f];
    }
    __syncthreads();
  }

  // ---- m' = U*mu ; const2 ; bf16 A-frag pack ----
  if(t<DDIM){
    float s=0.f;
    #pragma unroll 8
    for(int c=0;c<DDIM;c++) s += W[t*SA+c]*muS[c];
    ws_mp[k*DDIM+t]=s;
  }
  if(t==0) ws_c2[k] = logf(wts[k]) - hsum - 117.6241322f;
  #pragma unroll 1
  for(int s0=t;s0<2048;s0+=256){
    int l2=s0&63, dt2=(s0>>6)&3, kc=s0>>8;
    int row=dt2*32+(l2&31), colb=kc*16+((l2>>5)<<3);
    unsigned uu[4];
    #pragma unroll
    for(int h2=0;h2<4;h2++){
      unsigned lo=f2bf(W[row*SA+colb+2*h2]);
      unsigned hi=f2bf(W[row*SA+colb+2*h2+1]);
      uu[h2]=lo|(hi<<16);
    }
    uint4 wv; wv.x=uu[0]; wv.y=uu[1]; wv.z=uu[2]; wv.w=uu[3];
    ((uint4*)ufrag)[(size_t)k*2048+s0]=wv;
  }
}

// ---------------------------------------------------------------------------
// Main: 256 threads = 4 waves = d-tiles, full-K contraction per wave, X
// register-resident, U streamed from L2 with manual even/odd double buffer.
// (unchanged — validated rounds 3-5)
// ---------------------------------------------------------------------------
#define MAIN_BODY(UR, KK)                                                     \
  {                                                                           \
    const int kidx = (KK);                                                    \
    const float* mpk = &mpS[kidx*DDIM + dt*32 + 4*q];                         \
    float4 m0 = *(const float4*)(mpk);                                        \
    float4 m1 = *(const float4*)(mpk + 8);                                    \
    float4 m2 = *(const float4*)(mpk + 16);                                   \
    float4 m3 = *(const float4*)(mpk + 24);                                   \
    float mrow[16] = {m0.x,m0.y,m0.z,m0.w, m1.x,m1.y,m1.z,m1.w,               \
                      m2.x,m2.y,m2.z,m2.w, m3.x,m3.y,m3.z,m3.w};              \
    _Pragma("unroll")                                                         \
    for(int g=0; g<2; g++){                                                   \
      f32x16 a0 = {}, a1 = {};                                                \
      _Pragma("unroll")                                                       \
      for(int c=0; c<8; c++){                                                 \
        bf16x8 af = __builtin_bit_cast(bf16x8, UR[c]);                        \
        a0 = __builtin_amdgcn_mfma_f32_32x32x16_bf16(af, xf[2*g  ][c], a0, 0,0,0); \
        a1 = __builtin_amdgcn_mfma_f32_32x32x16_bf16(af, xf[2*g+1][c], a1, 0,0,0); \
      }                                                                       \
      float s0 = 0.f, s1 = 0.f;                                               \
      _Pragma("unroll")                                                       \
      for(int r=0;r<16;r++){                                                  \
        float d0 = a0[r]-mrow[r]; s0 += d0*d0;                                \
        float d1 = a1[r]-mrow[r]; s1 += d1*d1;                                \
      }                                                                       \
      s0 += __shfl_xor(s0, 32);                                               \
      s1 += __shfl_xor(s1, 32);                                               \
      if(lane < 32){                                                          \
        atomicAdd(&maha[kidx*DDIM + (2*g  )*32 + ln], s0);                    \
        atomicAdd(&maha[kidx*DDIM + (2*g+1)*32 + ln], s1);                    \
      }                                                                       \
    }                                                                         \
  }

__global__ __launch_bounds__(256,2) void k_main(const float* __restrict__ x,
                                                const uint4* __restrict__ uf,
                                                const float* __restrict__ ws_mp,
                                                const float* __restrict__ ws_c2,
                                                float* __restrict__ out){
  __shared__ float maha[KCOMP*DDIM];   // 16 KB [k][n]
  __shared__ float mpS[KCOMP*DDIM];    // 16 KB [k][d]
  __shared__ float c2s[KCOMP];
  const int t = threadIdx.x, lane = t&63, dt = t>>6;
  const int q = lane>>5, ln = lane&31;
  const size_t n0 = (size_t)blockIdx.x * 128;

  {
    float4 z = {0.f,0.f,0.f,0.f};
    float4* mz = (float4*)maha;
    mz[t] = z; mz[t+256] = z; mz[t+512] = z; mz[t+768] = z;
    const float4* s4 = (const float4*)ws_mp;
    float4* d4 = (float4*)mpS;
    d4[t] = s4[t]; d4[t+256] = s4[t+256]; d4[t+512] = s4[t+512]; d4[t+768] = s4[t+768];
    if(t < KCOMP) c2s[t] = ws_c2[t];
  }

  bf16x8 xf[4][8];
  {
    const float* xb = x + n0*DDIM + 8*q;
    #pragma unroll
    for(int it=0; it<4; it++){
      const float* rowp = xb + (size_t)(it*32 + ln)*DDIM;
      #pragma unroll
      for(int c=0; c<8; c++){
        float4 f0 = *(const float4*)(rowp + c*16);
        float4 f1 = *(const float4*)(rowp + c*16 + 4);
        union { unsigned short us[8]; bf16x8 v; } cvt;
        cvt.us[0]=f2bf(f0.x); cvt.us[1]=f2bf(f0.y); cvt.us[2]=f2bf(f0.z); cvt.us[3]=f2bf(f0.w);
        cvt.us[4]=f2bf(f1.x); cvt.us[5]=f2bf(f1.y); cvt.us[6]=f2bf(f1.z); cvt.us[7]=f2bf(f1.w);
        xf[it][c] = cvt.v;
      }
    }
  }

  uint4 uA[8], uB[8];
  #pragma unroll
  for(int c=0; c<8; c++) uA[c] = uf[(size_t)(c*4 + dt)*64 + lane];
  __syncthreads();

  #pragma unroll 1
  for(int k2=0;k2<KCOMP;k2+=2){
    #pragma unroll
    for(int c=0; c<8; c++)
      uB[c] = uf[(size_t)(k2+1)*2048 + (c*4 + dt)*64 + lane];
    MAIN_BODY(uA, k2)
    {
      const int kn = (k2+2)&(KCOMP-1);   // wraps to 0 on last iter (harmless)
      #pragma unroll
      for(int c=0; c<8; c++)
        uA[c] = uf[(size_t)kn*2048 + (c*4 + dt)*64 + lane];
    }
    MAIN_BODY(uB, k2+1)
  }
  __syncthreads();

  if(t < 128){
    float m_run = -INFINITY, s_run = 0.f;
    #pragma unroll 1
    for(int k=0;k<KCOMP;k++){
      float a  = c2s[k] - 0.5f*maha[k*DDIM + t];
      float nm = fmaxf(m_run, a);
      s_run = s_run*__expf(m_run-nm) + __expf(a-nm);
      m_run = nm;
    }
    out[n0 + t] = m_run + logf(s_run);
  }
}

// ---------------------------------------------------------------------------
extern "C" void kernel_launch(void* const* d_in, const int* in_sizes, int n_in,
                              void* d_out, int out_size, void* d_ws, size_t ws_size,
                              hipStream_t stream){
  const float* x   = (const float*)d_in[0];
  const float* mu  = (const float*)d_in[1];
  const float* cov = (const float*)d_in[2];
  const float* wts = (const float*)d_in[3];
  float* out = (float*)d_out;
  char*  ws  = (char*)d_ws;

  float*          wsMP = (float*)(ws);                 // 16 KB (m')
  float*          wsC2 = (float*)(ws + 16384);         // 128 B (const2)
  unsigned short* wsUF = (unsigned short*)(ws + 16640);// 1 MB (U bf16 frags)

  k_prep<<<KCOMP, 256, 0, stream>>>(cov, wts, mu, wsMP, wsC2, wsUF);
  k_main<<<NPTS/128, 256, 0, stream>>>(x, (const uint4*)wsUF, wsMP, wsC2, out);
}

// Round 7
// 226.778 us; speedup vs baseline: 2.1920x; 1.2130x over previous
//
#include <hip/hip_runtime.h>
#include <hip/hip_bf16.h>
#include <math.h>

#define KCOMP 32
#define DDIM  128
#define NPTS  65536
#define GMM_EPS 1e-6f
#define SA 129   // LDS row stride (odd -> conflict-free for scalar col access)

typedef __attribute__((ext_vector_type(8)))  __bf16 bf16x8;
typedef __attribute__((ext_vector_type(16))) float  f32x16;

__device__ __forceinline__ unsigned short f2bf(float f){
  unsigned u = __builtin_bit_cast(unsigned, f);
  u = (u + 0x7FFFu + ((u >> 16) & 1u)) >> 16;   // RNE
  return (unsigned short)u;
}
// v_readlane_b32: VALU->SGPR broadcast, ~2-4 cyc, NO LDS round trip.
// Lane index must be wave-uniform (here: compile-time constants).
__device__ __forceinline__ float rlane(float v, int lsrc){
  return __builtin_bit_cast(float, __builtin_amdgcn_readlane(__builtin_bit_cast(int, v), lsrc));
}

// ---------------------------------------------------------------------------
// chol_inv32: register-resident Cholesky + triangular inverse of one 32x32
// SPD block. One wave; lane c = column c. ALL array indices compile-time ->
// pure VGPR; ALL cross-lane via v_readlane (NOT __shfl/ds_bpermute — that
// was 100 us of lgkm-wait latency in round 6).
// Writes L rows into Ab (lower, zeros above), V = L^{-1} into Wb.
// Returns 0.5*sum_j log L[j][j]^2 (wave-uniform).
// ---------------------------------------------------------------------------
__device__ __noinline__ float chol_inv32(float* __restrict__ Ab,
                                         float* __restrict__ Wb,
                                         const int c){
  float ar[32], lr[32], rd[32], v[32];
  #pragma unroll
  for(int i=0;i<32;i++) ar[i] = Ab[i*SA + c];   // column c (symmetric block)
  float hl = 0.f;
  // right-looking rank-1 Cholesky: ar[j] (lane c) = A[j][c]; pivot via
  // readlane; stale lanes (c<j) compute garbage they never use.
  #pragma unroll
  for(int j=0;j<32;j++){
    float d   = rlane(ar[j], j);        // Schur diag = L[j][j]^2
    float rsd = rsqrtf(d);
    hl += logf(d);
    rd[j] = rsd;                        // 1/L[j][j]
    float Lcj  = ar[j]*rsd;             // L[c][j] (valid for c>=j)
    lr[j] = (c>=j) ? Lcj : 0.f;
    float coef = Lcj*rsd;               // A[c][j]/d
    #pragma unroll
    for(int i=j;i<32;i++){
      float bij = rlane(ar[i], j);      // A[i][j]  (uniform)
      ar[i] = fmaf(-bij, coef, ar[i]);  // A[i][c] -= L[i][j]*L[c][j]
    }
  }
  #pragma unroll
  for(int j=0;j<32;j++) Ab[c*SA + j] = lr[j];   // row c of L (zeros above diag)
  // forward substitution for V = L^{-1}: v[i] = V[i][c]; v[i]=0 for i<c falls
  // out naturally (s==0). L[i][p] broadcast from lane i's lr[p] via readlane.
  #pragma unroll
  for(int i=0;i<32;i++){
    float s = (i==c) ? 1.f : 0.f;
    #pragma unroll
    for(int p=0;p<i;p++) s = fmaf(-rlane(lr[p], i), v[p], s);
    v[i] = s * rd[i];
  }
  #pragma unroll
  for(int i=0;i<32;i++) Wb[i*SA + c] = v[i];
  return 0.5f*hl;
}

// ---------------------------------------------------------------------------
// k_prep: one block (256 thr) per component. Blocked Cholesky+inverse with
// register-resident serial math; panel solve & SYRK & inverse-levels as
// 4x4 reg-tiled LDS GEMMs; then m', const2, bf16 MFMA A-frag pack.
// ---------------------------------------------------------------------------
__global__ __launch_bounds__(256) void k_prep(const float* __restrict__ cov,
                                              const float* __restrict__ wts,
                                              const float* __restrict__ means,
                                              float* __restrict__ ws_mp,
                                              float* __restrict__ ws_c2,
                                              unsigned short* __restrict__ ufrag){
  __shared__ float A[DDIM*SA];      // 64.5 KB: cov -> L (lower)
  __shared__ float W[DDIM*SA];      // 64.5 KB: U = L^{-1} (lower), 0 above
  __shared__ float Tb[3*32*33];     // 12.4 KB: per-wave level-GEMM scratch
  __shared__ float muS[DDIM];
  const int t=threadIdx.x, w=t>>6, l=t&63, k=blockIdx.x;
  const int r0=(l>>3)*4, c0=(l&7)*4;

  // load cov (float4 global) -> A scalar LDS; zero W; stage mu
  const float4* cv4 = (const float4*)(cov + (size_t)k*DDIM*DDIM);
  #pragma unroll
  for(int v=0; v<16; v++){
    int idx4 = t + 256*v; float4 f = cv4[idx4];
    int e = idx4*4; int i = e>>7; int j = e&127;
    float* d = &A[i*SA+j]; d[0]=f.x; d[1]=f.y; d[2]=f.z; d[3]=f.w;
  }
  for(int z=t; z<DDIM*SA; z+=256) W[z] = 0.f;
  if(t<DDIM) muS[t] = means[k*DDIM+t];
  __syncthreads();
  if(t<DDIM) A[t*SA+t] += GMM_EPS;
  __syncthreads();

  static const int SYI[10]={1,2,2,3,3,3, 2,3,3, 3};
  static const int SYJ[10]={1,1,2,1,2,3, 2,2,3, 3};
  static const int SYO[5] ={0,6,9,10,10};

  float hsum = 0.f;
  #pragma unroll 1
  for(int b=0;b<4;b++){
    const int b32=b*32;
    // ---- register chol + inverse of diag block, wave 0 ----
    if(w==0) hsum += chol_inv32(&A[b32*SA+b32], &W[b32*SA+b32], l&31);
    __syncthreads();
    // ---- panel solve: L_ib = A_ib @ V^T  (unit = 32 rows per wave) ----
    if(w < 3-b){
      const int ibl = b+1+w;
      float acc[4][4]={};
      for(int kc=0;kc<32;kc+=4){
        float a_[4][4], b_[4][4];
        #pragma unroll
        for(int e=0;e<4;e++)
          #pragma unroll
          for(int g=0;g<4;g++){
            a_[e][g]=A[(32*ibl+r0+e)*SA + b32+kc+g];
            b_[e][g]=W[(b32+c0+e)*SA   + b32+kc+g];   // V[c0+e][kc+g]
          }
        #pragma unroll
        for(int e=0;e<4;e++)
          #pragma unroll
          for(int f=0;f<4;f++)
            acc[e][f]+=a_[e][0]*b_[f][0]+a_[e][1]*b_[f][1]
                      +a_[e][2]*b_[f][2]+a_[e][3]*b_[f][3];
      }
      // wave-lockstep: all reads above complete before these writes
      #pragma unroll
      for(int e=0;e<4;e++)
        #pragma unroll
        for(int f=0;f<4;f++)
          A[(32*ibl+r0+e)*SA + b32+c0+f] = acc[e][f];
    }
    __syncthreads();
    // ---- SYRK: A_ij -= L_ib @ L_jb^T ----
    #pragma unroll 1
    for(int u=SYO[b]+w; u<SYO[b+1]; u+=4){
      const int ui=SYI[u], uj=SYJ[u];
      float acc[4][4]={};
      for(int kc=0;kc<32;kc+=4){
        float a_[4][4], b_[4][4];
        #pragma unroll
        for(int e=0;e<4;e++)
          #pragma unroll
          for(int g=0;g<4;g++){
            a_[e][g]=A[(32*ui+r0+e)*SA + b32+kc+g];
            b_[e][g]=A[(32*uj+c0+e)*SA + b32+kc+g];
          }
        #pragma unroll
        for(int e=0;e<4;e++)
          #pragma unroll
          for(int f=0;f<4;f++)
            acc[e][f]+=a_[e][0]*b_[f][0]+a_[e][1]*b_[f][1]
                      +a_[e][2]*b_[f][2]+a_[e][3]*b_[f][3];
      }
      #pragma unroll
      for(int e=0;e<4;e++)
        #pragma unroll
        for(int f=0;f<4;f++)
          A[(32*ui+r0+e)*SA+32*uj+c0+f] -= acc[e][f];
    }
    __syncthreads();
  }

  // ---- inverse levels: U_ij = -V_i (sum_p L_ip U_pj) ----
  #pragma unroll 1
  for(int lev=1;lev<=3;lev++){
    if(w<4-lev){
      const int j=w, i=w+lev;
      float* T=&Tb[w*1056];
      float acc[4][4]={};
      #pragma unroll 1
      for(int p=j;p<i;p++){
        for(int kc=0;kc<32;kc+=4){
          float a_[4][4], b_[4][4];
          #pragma unroll
          for(int e=0;e<4;e++)
            #pragma unroll
            for(int g=0;g<4;g++){
              a_[e][g]=A[(32*i+r0+e)*SA + 32*p+kc+g];
              b_[e][g]=W[(32*p+kc+e)*SA + 32*j+c0+g];
            }
          #pragma unroll
          for(int e=0;e<4;e++)
            #pragma unroll
            for(int f=0;f<4;f++)
              acc[e][f]+=a_[e][0]*b_[0][f]+a_[e][1]*b_[1][f]
                        +a_[e][2]*b_[2][f]+a_[e][3]*b_[3][f];
        }
      }
      #pragma unroll
      for(int e=0;e<4;e++)
        #pragma unroll
        for(int f=0;f<4;f++)
          T[(r0+e)*33+c0+f]=acc[e][f];
      float ac2[4][4]={};
      for(int kc=0;kc<32;kc+=4){
        float a_[4][4], b_[4][4];
        #pragma unroll
        for(int e=0;e<4;e++)
          #pragma unroll
          for(int g=0;g<4;g++){
            a_[e][g]=W[(32*i+r0+e)*SA + 32*i+kc+g];
            b_[e][g]=T[(kc+e)*33 + c0+g];
          }
        #pragma unroll
        for(int e=0;e<4;e++)
          #pragma unroll
          for(int f=0;f<4;f++)
            ac2[e][f]+=a_[e][0]*b_[0][f]+a_[e][1]*b_[1][f]
                      +a_[e][2]*b_[2][f]+a_[e][3]*b_[3][f];
      }
      #pragma unroll
      for(int e=0;e<4;e++)
        #pragma unroll
        for(int f=0;f<4;f++)
          W[(32*i+r0+e)*SA+32*j+c0+f] = -ac2[e][f];
    }
    __syncthreads();
  }

  // ---- m' = U*mu ; const2 ; bf16 A-frag pack ----
  if(t<DDIM){
    float s=0.f;
    #pragma unroll 8
    for(int c=0;c<DDIM;c++) s += W[t*SA+c]*muS[c];
    ws_mp[k*DDIM+t]=s;
  }
  if(t==0) ws_c2[k] = logf(wts[k]) - hsum - 117.6241322f;
  #pragma unroll 1
  for(int s0=t;s0<2048;s0+=256){
    int l2=s0&63, dt2=(s0>>6)&3, kc=s0>>8;
    int row=dt2*32+(l2&31), colb=kc*16+((l2>>5)<<3);
    unsigned uu[4];
    #pragma unroll
    for(int h2=0;h2<4;h2++){
      unsigned lo=f2bf(W[row*SA+colb+2*h2]);
      unsigned hi=f2bf(W[row*SA+colb+2*h2+1]);
      uu[h2]=lo|(hi<<16);
    }
    uint4 wv; wv.x=uu[0]; wv.y=uu[1]; wv.z=uu[2]; wv.w=uu[3];
    ((uint4*)ufrag)[(size_t)k*2048+s0]=wv;
  }
}

// ---------------------------------------------------------------------------
// Main: 256 threads = 4 waves = d-tiles, full-K contraction per wave, X
// register-resident, U streamed from L2 with manual even/odd double buffer.
// (unchanged — validated rounds 3-6)
// ---------------------------------------------------------------------------
#define MAIN_BODY(UR, KK)                                                     \
  {                                                                           \
    const int kidx = (KK);                                                    \
    const float* mpk = &mpS[kidx*DDIM + dt*32 + 4*q];                         \
    float4 m0 = *(const float4*)(mpk);                                        \
    float4 m1 = *(const float4*)(mpk + 8);                                    \
    float4 m2 = *(const float4*)(mpk + 16);                                   \
    float4 m3 = *(const float4*)(mpk + 24);                                   \
    float mrow[16] = {m0.x,m0.y,m0.z,m0.w, m1.x,m1.y,m1.z,m1.w,               \
                      m2.x,m2.y,m2.z,m2.w, m3.x,m3.y,m3.z,m3.w};              \
    _Pragma("unroll")                                                         \
    for(int g=0; g<2; g++){                                                   \
      f32x16 a0 = {}, a1 = {};                                                \
      _Pragma("unroll")                                                       \
      for(int c=0; c<8; c++){                                                 \
        bf16x8 af = __builtin_bit_cast(bf16x8, UR[c]);                        \
        a0 = __builtin_amdgcn_mfma_f32_32x32x16_bf16(af, xf[2*g  ][c], a0, 0,0,0); \
        a1 = __builtin_amdgcn_mfma_f32_32x32x16_bf16(af, xf[2*g+1][c], a1, 0,0,0); \
      }                                                                       \
      float s0 = 0.f, s1 = 0.f;                                               \
      _Pragma("unroll")                                                       \
      for(int r=0;r<16;r++){                                                  \
        float d0 = a0[r]-mrow[r]; s0 += d0*d0;                                \
        float d1 = a1[r]-mrow[r]; s1 += d1*d1;                                \
      }                                                                       \
      s0 += __shfl_xor(s0, 32);                                               \
      s1 += __shfl_xor(s1, 32);                                               \
      if(lane < 32){                                                          \
        atomicAdd(&maha[kidx*DDIM + (2*g  )*32 + ln], s0);                    \
        atomicAdd(&maha[kidx*DDIM + (2*g+1)*32 + ln], s1);                    \
      }                                                                       \
    }                                                                         \
  }

__global__ __launch_bounds__(256,2) void k_main(const float* __restrict__ x,
                                                const uint4* __restrict__ uf,
                                                const float* __restrict__ ws_mp,
                                                const float* __restrict__ ws_c2,
                                                float* __restrict__ out){
  __shared__ float maha[KCOMP*DDIM];   // 16 KB [k][n]
  __shared__ float mpS[KCOMP*DDIM];    // 16 KB [k][d]
  __shared__ float c2s[KCOMP];
  const int t = threadIdx.x, lane = t&63, dt = t>>6;
  const int q = lane>>5, ln = lane&31;
  const size_t n0 = (size_t)blockIdx.x * 128;

  {
    float4 z = {0.f,0.f,0.f,0.f};
    float4* mz = (float4*)maha;
    mz[t] = z; mz[t+256] = z; mz[t+512] = z; mz[t+768] = z;
    const float4* s4 = (const float4*)ws_mp;
    float4* d4 = (float4*)mpS;
    d4[t] = s4[t]; d4[t+256] = s4[t+256]; d4[t+512] = s4[t+512]; d4[t+768] = s4[t+768];
    if(t < KCOMP) c2s[t] = ws_c2[t];
  }

  bf16x8 xf[4][8];
  {
    const float* xb = x + n0*DDIM + 8*q;
    #pragma unroll
    for(int it=0; it<4; it++){
      const float* rowp = xb + (size_t)(it*32 + ln)*DDIM;
      #pragma unroll
      for(int c=0; c<8; c++){
        float4 f0 = *(const float4*)(rowp + c*16);
        float4 f1 = *(const float4*)(rowp + c*16 + 4);
        union { unsigned short us[8]; bf16x8 v; } cvt;
        cvt.us[0]=f2bf(f0.x); cvt.us[1]=f2bf(f0.y); cvt.us[2]=f2bf(f0.z); cvt.us[3]=f2bf(f0.w);
        cvt.us[4]=f2bf(f1.x); cvt.us[5]=f2bf(f1.y); cvt.us[6]=f2bf(f1.z); cvt.us[7]=f2bf(f1.w);
        xf[it][c] = cvt.v;
      }
    }
  }

  uint4 uA[8], uB[8];
  #pragma unroll
  for(int c=0; c<8; c++) uA[c] = uf[(size_t)(c*4 + dt)*64 + lane];
  __syncthreads();

  #pragma unroll 1
  for(int k2=0;k2<KCOMP;k2+=2){
    #pragma unroll
    for(int c=0; c<8; c++)
      uB[c] = uf[(size_t)(k2+1)*2048 + (c*4 + dt)*64 + lane];
    MAIN_BODY(uA, k2)
    {
      const int kn = (k2+2)&(KCOMP-1);   // wraps to 0 on last iter (harmless)
      #pragma unroll
      for(int c=0; c<8; c++)
        uA[c] = uf[(size_t)kn*2048 + (c*4 + dt)*64 + lane];
    }
    MAIN_BODY(uB, k2+1)
  }
  __syncthreads();

  if(t < 128){
    float m_run = -INFINITY, s_run = 0.f;
    #pragma unroll 1
    for(int k=0;k<KCOMP;k++){
      float a  = c2s[k] - 0.5f*maha[k*DDIM + t];
      float nm = fmaxf(m_run, a);
      s_run = s_run*__expf(m_run-nm) + __expf(a-nm);
      m_run = nm;
    }
    out[n0 + t] = m_run + logf(s_run);
  }
}

// ---------------------------------------------------------------------------
extern "C" void kernel_launch(void* const* d_in, const int* in_sizes, int n_in,
                              void* d_out, int out_size, void* d_ws, size_t ws_size,
                              hipStream_t stream){
  const float* x   = (const float*)d_in[0];
  const float* mu  = (const float*)d_in[1];
  const float* cov = (const float*)d_in[2];
  const float* wts = (const float*)d_in[3];
  float* out = (float*)d_out;
  char*  ws  = (char*)d_ws;

  float*          wsMP = (float*)(ws);                 // 16 KB (m')
  float*          wsC2 = (float*)(ws + 16384);         // 128 B (const2)
  unsigned short* wsUF = (unsigned short*)(ws + 16640);// 1 MB (U bf16 frags)

  k_prep<<<KCOMP, 256, 0, stream>>>(cov, wts, mu, wsMP, wsC2, wsUF);
  k_main<<<NPTS/128, 256, 0, stream>>>(x, (const uint4*)wsUF, wsMP, wsC2, out);
}